// Round 1
// baseline (1314.884 us; speedup 1.0000x reference)
//
#include <hip/hip_runtime.h>
#include <cstdint>
#include <cstddef>

#define D 128
#define F_IN 256

// ---------------- utility kernels ----------------

__global__ void count_edges_k(const int* __restrict__ idx, int* __restrict__ cnt, int E) {
  int e = blockIdx.x * blockDim.x + threadIdx.x;
  if (e < E) atomicAdd(&cnt[idx[e]], 1);
}

__global__ void inv_deg_k(const int* __restrict__ cnt, float* __restrict__ inv, int n) {
  int i = blockIdx.x * blockDim.x + threadIdx.x;
  if (i < n) {
    int c = cnt[i];
    inv[i] = 1.0f / (float)(c > 1 ? c : 1);
  }
}

// exclusive scan over n ints, chunk = 1024 per block (256 thr * 4)
__global__ void scan1_k(const int* __restrict__ cnt, int* __restrict__ bsum, int n) {
  __shared__ int sd[256];
  int t = threadIdx.x;
  int base = blockIdx.x * 1024 + t * 4;
  int s = 0;
#pragma unroll
  for (int j = 0; j < 4; ++j) { int i = base + j; if (i < n) s += cnt[i]; }
  sd[t] = s;
  __syncthreads();
  if (t == 0) { int tot = 0; for (int i = 0; i < 256; ++i) tot += sd[i]; bsum[blockIdx.x] = tot; }
}

__global__ void scan2_k(int* __restrict__ bsum, int nb) {
  if (threadIdx.x == 0 && blockIdx.x == 0) {
    int run = 0;
    for (int i = 0; i < nb; ++i) { int v = bsum[i]; bsum[i] = run; run += v; }
  }
}

__global__ void scan3_k(const int* __restrict__ cnt, const int* __restrict__ bsum,
                        int* __restrict__ row, int n, int total) {
  __shared__ int sd[256];
  __shared__ int sx[256];
  int t = threadIdx.x;
  int base = blockIdx.x * 1024 + t * 4;
  int s = 0;
#pragma unroll
  for (int j = 0; j < 4; ++j) { int i = base + j; if (i < n) s += cnt[i]; }
  sd[t] = s;
  __syncthreads();
  if (t == 0) {
    int run = bsum[blockIdx.x];
    for (int i = 0; i < 256; ++i) { sx[i] = run; run += sd[i]; }
  }
  __syncthreads();
  int run = sx[t];
#pragma unroll
  for (int j = 0; j < 4; ++j) {
    int i = base + j;
    if (i < n) { row[i] = run; run += cnt[i]; }
  }
  if (blockIdx.x == 0 && t == 0) row[n] = total;
}

__global__ void fill_csr_k(const int* __restrict__ key, const int* __restrict__ other,
                           const int* __restrict__ row, int* __restrict__ cur,
                           int* __restrict__ csr, int E) {
  int e = blockIdx.x * blockDim.x + threadIdx.x;
  if (e < E) {
    int s = key[e];
    int p = atomicAdd(&cur[s], 1);
    csr[row[s] + p] = other[e];
  }
}

__global__ void gather_rows_k(const float* __restrict__ emb, const int* __restrict__ ids,
                              float* __restrict__ o, int n) {
  int i = blockIdx.x * blockDim.x + threadIdx.x;  // float4 index over n*32
  if (i >= n * (D / 4)) return;
  int r = i >> 5;
  int c = (i & 31) << 2;
  int srcrow = ids[r];
  *(float4*)(o + (size_t)r * D + c) = *(const float4*)(emb + (size_t)srcrow * D + c);
}

// pull-based mean aggregation: one 64-lane wave per node, float2 per lane
__global__ __launch_bounds__(256) void aggregate_k(
    const float* __restrict__ tab, const int* __restrict__ rowp,
    const int* __restrict__ idx, const float* __restrict__ invd,
    float* __restrict__ aggout, int n)
{
  int node = blockIdx.x * 4 + (threadIdx.x >> 6);
  if (node >= n) return;
  int lane = threadIdx.x & 63;
  int b = rowp[node], e = rowp[node + 1];
  float ax = 0.f, ay = 0.f;
  for (int p = b; p < e; ++p) {
    int nb = idx[p];
    float2 v = *(const float2*)(tab + (size_t)nb * D + lane * 2);
    ax += v.x; ay += v.y;
  }
  float s = invd[node];
  *(float2*)(aggout + (size_t)node * D + lane * 2) = make_float2(ax * s, ay * s);
}

// out[m][0:128] = A[m][0:K1] @ WA^T + B[m][0:K2] @ WB^T + bias  (optional relu)
// 128-row x 128-col tile per block, 256 threads, 8x8 micro-tile (stride-16 map)
template<int K1, int K2, bool RELU>
__global__ __launch_bounds__(256) void fused_gemm_k(
    const float* __restrict__ A, const float* __restrict__ WA,
    const float* __restrict__ B, const float* __restrict__ WB,
    const float* __restrict__ bias, float* __restrict__ out, int M)
{
  constexpr int PAD = 34;   // float2-aligned, 2-way bank alias max (free)
  constexpr int KC = 32;
  __shared__ float As[128 * PAD];
  __shared__ float Ws[128 * PAD];
  const int tid = threadIdx.x;
  const int tx = tid & 15;   // col group: cols tx + 16j
  const int ty = tid >> 4;   // row group: rows ty + 16i
  const int row0 = blockIdx.x * 128;

  float acc[8][8];
#pragma unroll
  for (int j = 0; j < 8; ++j) {
    float bj = bias[tx + 16 * j];
#pragma unroll
    for (int i = 0; i < 8; ++i) acc[i][j] = bj;
  }

  constexpr int NK1 = K1 / KC;
  constexpr int NK2 = (K2 > 0) ? (K2 / KC) : 0;
#pragma unroll 1
  for (int ch = 0; ch < NK1 + NK2; ++ch) {
    const float* Ap; const float* Wp; int stride; int k0;
    if (ch < NK1) { Ap = A; Wp = WA; stride = K1; k0 = ch * KC; }
    else          { Ap = B; Wp = WB; stride = K2; k0 = (ch - NK1) * KC; }
    if (ch) __syncthreads();
#pragma unroll
    for (int q = 0; q < 4; ++q) {
      int idx = tid + 256 * q;       // 0..1023
      int r = idx >> 3;              // 0..127
      int c4 = (idx & 7) << 2;       // 0,4,...,28
      int gr = row0 + r;
      float4 v = make_float4(0.f, 0.f, 0.f, 0.f);
      if (gr < M) v = *(const float4*)(Ap + (size_t)gr * stride + k0 + c4);
      float* dst = &As[r * PAD + c4];
      *(float2*)(dst)     = make_float2(v.x, v.y);
      *(float2*)(dst + 2) = make_float2(v.z, v.w);
    }
#pragma unroll
    for (int q = 0; q < 4; ++q) {
      int idx = tid + 256 * q;
      int r = idx >> 3;              // output feature 0..127
      int c4 = (idx & 7) << 2;
      float4 v = *(const float4*)(Wp + (size_t)r * stride + k0 + c4);
      float* dst = &Ws[r * PAD + c4];
      *(float2*)(dst)     = make_float2(v.x, v.y);
      *(float2*)(dst + 2) = make_float2(v.z, v.w);
    }
    __syncthreads();
#pragma unroll
    for (int kk = 0; kk < KC; kk += 2) {
      float2 a2[8], w2[8];
#pragma unroll
      for (int i = 0; i < 8; ++i) a2[i] = *(const float2*)&As[(ty + 16 * i) * PAD + kk];
#pragma unroll
      for (int j = 0; j < 8; ++j) w2[j] = *(const float2*)&Ws[(tx + 16 * j) * PAD + kk];
#pragma unroll
      for (int i = 0; i < 8; ++i)
#pragma unroll
        for (int j = 0; j < 8; ++j) {
          acc[i][j] = fmaf(a2[i].x, w2[j].x, acc[i][j]);
          acc[i][j] = fmaf(a2[i].y, w2[j].y, acc[i][j]);
        }
    }
  }
#pragma unroll
  for (int i = 0; i < 8; ++i) {
    int gr = row0 + ty + 16 * i;
    if (gr < M) {
#pragma unroll
      for (int j = 0; j < 8; ++j) {
        float v = acc[i][j];
        if (RELU) v = fmaxf(v, 0.f);
        out[(size_t)gr * D + tx + 16 * j] = v;
      }
    }
  }
}

// one 32-lane group per query: float4 loads + shuffle reduce
__global__ __launch_bounds__(256) void classify_k(
    const float* __restrict__ ht, const float* __restrict__ hm,
    const int* __restrict__ qs, const int* __restrict__ qd,
    const float* __restrict__ w, const float* __restrict__ bptr,
    float* __restrict__ out, int Q)
{
  int g = blockIdx.x * 8 + (threadIdx.x >> 5);
  if (g >= Q) return;
  int l = threadIdx.x & 31;
  int s = qs[g], dd = qd[g];
  float4 a  = *(const float4*)(ht + (size_t)s * D + l * 4);
  float4 wa = *(const float4*)(w + l * 4);
  float4 b  = *(const float4*)(hm + (size_t)dd * D + l * 4);
  float4 wb = *(const float4*)(w + D + l * 4);
  float acc = a.x * wa.x + a.y * wa.y + a.z * wa.z + a.w * wa.w
            + b.x * wb.x + b.y * wb.y + b.z * wb.z + b.w * wb.w;
#pragma unroll
  for (int m = 16; m >= 1; m >>= 1) acc += __shfl_xor(acc, m, 64);
  if (l == 0) out[g] = acc + bptr[0];
}

// ---------------- launcher ----------------

extern "C" void kernel_launch(void* const* d_in, const int* in_sizes, int n_in,
                              void* d_out, int out_size, void* d_ws, size_t ws_size,
                              hipStream_t stream)
{
  const float* x_thesis = (const float*)d_in[0];
  const int*   mentor_id = (const int*)d_in[1];
  const int*   esrc = (const int*)d_in[2];
  const int*   edst = (const int*)d_in[3];
  const int*   qsrc = (const int*)d_in[4];
  const int*   qdst = (const int*)d_in[5];
  const float* lin_w = (const float*)d_in[6];
  const float* lin_b = (const float*)d_in[7];
  const float* prof  = (const float*)d_in[8];
  const float* Wn_sup = (const float*)d_in[9];
  const float* Wr_sup = (const float*)d_in[10];
  const float* b_sup  = (const float*)d_in[11];
  const float* Wn_rev = (const float*)d_in[12];
  const float* Wr_rev = (const float*)d_in[13];
  const float* b_rev  = (const float*)d_in[14];
  const float* cls_w  = (const float*)d_in[15];
  const float* cls_b  = (const float*)d_in[16];

  const int NT = in_sizes[0] / F_IN;
  const int NM = in_sizes[1];
  const int E  = in_sizes[2];
  const int Q  = in_sizes[4];
  const int L  = in_sizes[11] / D;

  char* wsb = (char*)d_ws;
  size_t off = 0;
  auto alloc = [&](size_t bytes) {
    void* p = wsb + off;
    off = (off + bytes + 255) & ~(size_t)255;
    return p;
  };
  float* h_t    = (float*)alloc((size_t)NT * D * 4);
  float* a_t    = (float*)alloc((size_t)NT * D * 4);
  float* h_m    = (float*)alloc((size_t)NM * D * 4);
  float* a_m    = (float*)alloc((size_t)NM * D * 4);
  float* invd_t = (float*)alloc((size_t)NT * 4);
  float* invd_m = (float*)alloc((size_t)NM * 4);
  int* cnt_t = (int*)alloc((size_t)NT * 4);
  int* cnt_m = (int*)alloc((size_t)NM * 4);
  int* cur_t = (int*)alloc((size_t)NT * 4);
  int* cur_m = (int*)alloc((size_t)NM * 4);
  int* row_t = (int*)alloc(((size_t)NT + 1) * 4);
  int* row_m = (int*)alloc(((size_t)NM + 1) * 4);
  int* csr_t = (int*)alloc((size_t)E * 4);   // mentor ids grouped by thesis
  int* csr_m = (int*)alloc((size_t)E * 4);   // thesis ids grouped by mentor
  int* bsum_t = (int*)alloc(1024 * 4);
  int* bsum_m = (int*)alloc(1024 * 4);
  (void)n_in; (void)out_size; (void)ws_size;

  hipMemsetAsync(cnt_t, 0, (size_t)NT * 4, stream);
  hipMemsetAsync(cnt_m, 0, (size_t)NM * 4, stream);
  hipMemsetAsync(cur_t, 0, (size_t)NT * 4, stream);
  hipMemsetAsync(cur_m, 0, (size_t)NM * 4, stream);

  int eb = (E + 255) / 256;
  count_edges_k<<<eb, 256, 0, stream>>>(esrc, cnt_t, E);
  count_edges_k<<<eb, 256, 0, stream>>>(edst, cnt_m, E);
  inv_deg_k<<<(NT + 255) / 256, 256, 0, stream>>>(cnt_t, invd_t, NT);
  inv_deg_k<<<(NM + 255) / 256, 256, 0, stream>>>(cnt_m, invd_m, NM);

  int nbt = (NT + 1023) / 1024, nbm = (NM + 1023) / 1024;
  scan1_k<<<nbt, 256, 0, stream>>>(cnt_t, bsum_t, NT);
  scan2_k<<<1, 64, 0, stream>>>(bsum_t, nbt);
  scan3_k<<<nbt, 256, 0, stream>>>(cnt_t, bsum_t, row_t, NT, E);
  scan1_k<<<nbm, 256, 0, stream>>>(cnt_m, bsum_m, NM);
  scan2_k<<<1, 64, 0, stream>>>(bsum_m, nbm);
  scan3_k<<<nbm, 256, 0, stream>>>(cnt_m, bsum_m, row_m, NM, E);

  fill_csr_k<<<eb, 256, 0, stream>>>(esrc, edst, row_t, cur_t, csr_t, E);
  fill_csr_k<<<eb, 256, 0, stream>>>(edst, esrc, row_m, cur_m, csr_m, E);

  gather_rows_k<<<((NM * (D / 4)) + 255) / 256, 256, 0, stream>>>(prof, mentor_id, h_m, NM);

  fused_gemm_k<256, 0, false><<<(NT + 127) / 128, 256, 0, stream>>>(
      x_thesis, lin_w, nullptr, nullptr, lin_b, h_t, NT);

  for (int l = 0; l < L; ++l) {
    aggregate_k<<<(NM + 3) / 4, 256, 0, stream>>>(h_t, row_m, csr_m, invd_m, a_m, NM);
    aggregate_k<<<(NT + 3) / 4, 256, 0, stream>>>(h_m, row_t, csr_t, invd_t, a_t, NT);

    const float* wns = Wn_sup + (size_t)l * D * D;
    const float* wrs = Wr_sup + (size_t)l * D * D;
    const float* bs  = b_sup + (size_t)l * D;
    const float* wnr = Wn_rev + (size_t)l * D * D;
    const float* wrr = Wr_rev + (size_t)l * D * D;
    const float* br  = b_rev + (size_t)l * D;
    if (l < L - 1) {
      fused_gemm_k<128, 128, true><<<(NM + 127) / 128, 256, 0, stream>>>(a_m, wns, h_m, wrs, bs, a_m, NM);
      fused_gemm_k<128, 128, true><<<(NT + 127) / 128, 256, 0, stream>>>(a_t, wnr, h_t, wrr, br, a_t, NT);
    } else {
      fused_gemm_k<128, 128, false><<<(NM + 127) / 128, 256, 0, stream>>>(a_m, wns, h_m, wrs, bs, a_m, NM);
      fused_gemm_k<128, 128, false><<<(NT + 127) / 128, 256, 0, stream>>>(a_t, wnr, h_t, wrr, br, a_t, NT);
    }
    float* tmp;
    tmp = h_t; h_t = a_t; a_t = tmp;
    tmp = h_m; h_m = a_m; a_m = tmp;
  }

  classify_k<<<(Q + 7) / 8, 256, 0, stream>>>(h_t, h_m, qsrc, qdst, cls_w, cls_b,
                                              (float*)d_out, Q);
}

// Round 2
// 557.644 us; speedup vs baseline: 2.3579x; 2.3579x over previous
//
#include <hip/hip_runtime.h>
#include <cstdint>
#include <cstddef>

#define D 128
#define F_IN 256

typedef __attribute__((ext_vector_type(8))) short bf16x8;
typedef __attribute__((ext_vector_type(4))) float f32x4;

__device__ __forceinline__ unsigned short f2bs(float f) {
  unsigned int x = __builtin_bit_cast(unsigned int, f);
  x = x + 0x7fffu + ((x >> 16) & 1u);           // round-to-nearest-even
  return (unsigned short)(x >> 16);
}
__device__ __forceinline__ float b2f(unsigned int lo16) {
  unsigned int x = lo16 << 16;
  return __builtin_bit_cast(float, x);
}
__device__ __forceinline__ void gl_lds16(const unsigned short* g, unsigned short* l) {
  __builtin_amdgcn_global_load_lds(
      (__attribute__((address_space(1))) void*)g,
      (__attribute__((address_space(3))) void*)l, 16, 0, 0);
}

// ---------------- CSR build ----------------

__global__ void count_edges_k(const int* __restrict__ idx, int* __restrict__ cnt, int E) {
  int e = blockIdx.x * blockDim.x + threadIdx.x;
  if (e < E) atomicAdd(&cnt[idx[e]], 1);
}

__global__ void inv_deg_k(const int* __restrict__ cnt, float* __restrict__ inv, int n) {
  int i = blockIdx.x * blockDim.x + threadIdx.x;
  if (i < n) {
    int c = cnt[i];
    inv[i] = 1.0f / (float)(c > 1 ? c : 1);
  }
}

__global__ void scan1_k(const int* __restrict__ cnt, int* __restrict__ bsum, int n) {
  __shared__ int sd[256];
  int t = threadIdx.x;
  int base = blockIdx.x * 1024 + t * 4;
  int s = 0;
#pragma unroll
  for (int j = 0; j < 4; ++j) { int i = base + j; if (i < n) s += cnt[i]; }
  sd[t] = s;
  __syncthreads();
  if (t == 0) { int tot = 0; for (int i = 0; i < 256; ++i) tot += sd[i]; bsum[blockIdx.x] = tot; }
}

__global__ void scan2_k(int* __restrict__ bsum, int nb) {
  if (threadIdx.x == 0 && blockIdx.x == 0) {
    int run = 0;
    for (int i = 0; i < nb; ++i) { int v = bsum[i]; bsum[i] = run; run += v; }
  }
}

__global__ void scan3_k(const int* __restrict__ cnt, const int* __restrict__ bsum,
                        int* __restrict__ row, int n, int total) {
  __shared__ int sd[256];
  __shared__ int sx[256];
  int t = threadIdx.x;
  int base = blockIdx.x * 1024 + t * 4;
  int s = 0;
#pragma unroll
  for (int j = 0; j < 4; ++j) { int i = base + j; if (i < n) s += cnt[i]; }
  sd[t] = s;
  __syncthreads();
  if (t == 0) {
    int run = bsum[blockIdx.x];
    for (int i = 0; i < 256; ++i) { sx[i] = run; run += sd[i]; }
  }
  __syncthreads();
  int run = sx[t];
#pragma unroll
  for (int j = 0; j < 4; ++j) {
    int i = base + j;
    if (i < n) { row[i] = run; run += cnt[i]; }
  }
  if (blockIdx.x == 0 && t == 0) row[n] = total;
}

__global__ void fill_csr_k(const int* __restrict__ key, const int* __restrict__ other,
                           const int* __restrict__ row, int* __restrict__ cur,
                           int* __restrict__ csr, int E) {
  int e = blockIdx.x * blockDim.x + threadIdx.x;
  if (e < E) {
    int s = key[e];
    int p = atomicAdd(&cur[s], 1);
    csr[row[s] + p] = other[e];
  }
}

// ---------------- converts ----------------

// n8 = element count / 8
__global__ void convert_k(const float* __restrict__ s, unsigned short* __restrict__ d, int n8) {
  int i = blockIdx.x * blockDim.x + threadIdx.x;
  if (i >= n8) return;
  const float4* sp = (const float4*)(s + (size_t)i * 8);
  float4 a = sp[0], b = sp[1];
  uint4 o;
  o.x = (unsigned)f2bs(a.x) | ((unsigned)f2bs(a.y) << 16);
  o.y = (unsigned)f2bs(a.z) | ((unsigned)f2bs(a.w) << 16);
  o.z = (unsigned)f2bs(b.x) | ((unsigned)f2bs(b.y) << 16);
  o.w = (unsigned)f2bs(b.z) | ((unsigned)f2bs(b.w) << 16);
  *(uint4*)(d + (size_t)i * 8) = o;
}

// gather prof rows by id and convert to bf16 (h_m init)
__global__ void gather_conv_k(const float* __restrict__ emb, const int* __restrict__ ids,
                              unsigned short* __restrict__ o, int n) {
  int i = blockIdx.x * blockDim.x + threadIdx.x;   // n*16 chunks of 8
  if (i >= n * 16) return;
  int r = i >> 4, c = (i & 15) * 8;
  const float* s = emb + (size_t)ids[r] * D + c;
  float4 a = *(const float4*)s, b = *(const float4*)(s + 4);
  uint4 v;
  v.x = (unsigned)f2bs(a.x) | ((unsigned)f2bs(a.y) << 16);
  v.y = (unsigned)f2bs(a.z) | ((unsigned)f2bs(a.w) << 16);
  v.z = (unsigned)f2bs(b.x) | ((unsigned)f2bs(b.y) << 16);
  v.w = (unsigned)f2bs(b.z) | ((unsigned)f2bs(b.w) << 16);
  *(uint4*)(o + (size_t)r * D + c) = v;
}

// ---------------- aggregation (pull, bf16) ----------------

__global__ __launch_bounds__(256) void aggregate_k(
    const unsigned short* __restrict__ tab, const int* __restrict__ rowp,
    const int* __restrict__ idx, const float* __restrict__ invd,
    unsigned short* __restrict__ aggout, int n)
{
  int node = blockIdx.x * 4 + (threadIdx.x >> 6);
  if (node >= n) return;
  int lane = threadIdx.x & 63;
  int b = rowp[node], e = rowp[node + 1];
  float ax = 0.f, ay = 0.f;
  for (int p = b; p < e; ++p) {
    int nb = idx[p];
    unsigned int v = *(const unsigned int*)(tab + (size_t)nb * D + lane * 2);
    ax += b2f(v & 0xffffu);
    ay += b2f(v >> 16);
  }
  float s = invd[node];
  unsigned int o = (unsigned)f2bs(ax * s) | ((unsigned)f2bs(ay * s) << 16);
  *(unsigned int*)(aggout + (size_t)node * D + lane * 2) = o;
}

// ---------------- bf16 MFMA fused dual GEMM ----------------
// out[m][0:128] = A[m][0:K1]@WA^T + B[m][0:K2]@WB^T + bias, optional ReLU.
// 128x128 tile, 4 waves (64x64 each), BK=32, mfma_f32_16x16x32_bf16.

template<int K1, int K2, bool RELU>
__global__ __launch_bounds__(256) void gemm_bf16_k(
    const unsigned short* __restrict__ A, const unsigned short* __restrict__ WA,
    const unsigned short* __restrict__ B, const unsigned short* __restrict__ WB,
    const float* __restrict__ bias, unsigned short* __restrict__ out, int M)
{
  struct SMt { unsigned short A[128 * 32]; unsigned short W[128 * 32]; };
  __shared__ union { SMt t; unsigned short o[4][4096]; } sm;

  const int tid = threadIdx.x;
  const int w  = tid >> 6;
  const int l  = tid & 63;
  const int wr = w >> 1, wc = w & 1;
  const int lr = l & 15, kg = l >> 4;
  const int row0 = blockIdx.x * 128;
  const int srow = l >> 2;          // staging: row-within-chunk
  const int skk  = (l & 3) * 8;     // staging: k elem offset

  f32x4 acc[4][4] = {};

  constexpr int NK1 = K1 / 32;
  constexpr int NK2 = (K2 > 0) ? (K2 / 32) : 0;

#pragma unroll 1
  for (int st = 0; st < NK1 + NK2; ++st) {
    const unsigned short* Ap; const unsigned short* Wp; int K; int k0;
    if (st < NK1) { Ap = A; Wp = WA; K = K1; k0 = st * 32; }
    else          { Ap = B; Wp = WB; K = K2; k0 = (st - NK1) * 32; }
    if (st) __syncthreads();
#pragma unroll
    for (int q = 0; q < 2; ++q) {
      int c = w * 2 + q;            // chunk 0..7 (wave-uniform)
      int r = c * 16 + srow;        // tile row 0..127
      int gr = row0 + r;
      if (gr < M) gl_lds16(Ap + (size_t)gr * K + k0 + skk, &sm.t.A[c * 512 + l * 8]);
      gl_lds16(Wp + (size_t)r * K + k0 + skk, &sm.t.W[c * 512 + l * 8]);
    }
    __syncthreads();                // drains vmcnt before use
    bf16x8 aF[4], bF[4];
#pragma unroll
    for (int i = 0; i < 4; ++i)
      aF[i] = *(const bf16x8*)&sm.t.A[(wr * 64 + i * 16 + lr) * 32 + kg * 8];
#pragma unroll
    for (int j = 0; j < 4; ++j)
      bF[j] = *(const bf16x8*)&sm.t.W[(wc * 64 + j * 16 + lr) * 32 + kg * 8];
#pragma unroll
    for (int i = 0; i < 4; ++i)
#pragma unroll
      for (int j = 0; j < 4; ++j)
        acc[i][j] = __builtin_amdgcn_mfma_f32_16x16x32_bf16(aF[i], bF[j], acc[i][j], 0, 0, 0);
  }

  __syncthreads();                  // tiles no longer needed; reuse LDS for output staging
  float bn[4];
#pragma unroll
  for (int j = 0; j < 4; ++j) bn[j] = bias[wc * 64 + j * 16 + lr];
  unsigned short* ow = sm.o[w];
#pragma unroll
  for (int i = 0; i < 4; ++i)
#pragma unroll
    for (int j = 0; j < 4; ++j) {
      f32x4 v = acc[i][j];
#pragma unroll
      for (int r = 0; r < 4; ++r) {
        float x = v[r] + bn[j];
        if (RELU) x = fmaxf(x, 0.f);
        ow[(i * 16 + kg * 4 + r) * 64 + j * 16 + lr] = f2bs(x);
      }
    }
  // same-wave readback -> coalesced 16B global stores
#pragma unroll
  for (int q = 0; q < 8; ++q) {
    int u = q * 64 + l;             // 16B unit in the wave's 8KB staging
    int lrow = u >> 3;
    int cu = (u & 7) * 8;
    int gr = row0 + wr * 64 + lrow;
    if (gr < M)
      *(uint4*)(out + (size_t)gr * D + wc * 64 + cu) = *(const uint4*)&ow[lrow * 64 + cu];
  }
}

// ---------------- classifier ----------------

__global__ __launch_bounds__(256) void classify_k(
    const unsigned short* __restrict__ ht, const unsigned short* __restrict__ hm,
    const int* __restrict__ qs, const int* __restrict__ qd,
    const float* __restrict__ w, const float* __restrict__ bptr,
    float* __restrict__ out, int Q)
{
  int g = blockIdx.x * 8 + (threadIdx.x >> 5);
  if (g >= Q) return;
  int l = threadIdx.x & 31;
  const unsigned short* src = (l < 16)
      ? ht + (size_t)qs[g] * D + l * 8
      : hm + (size_t)qd[g] * D + (l - 16) * 8;
  uint4 v = *(const uint4*)src;
  const float* wp = w + l * 8;
  float acc = 0.f;
  acc += b2f(v.x & 0xffffu) * wp[0];
  acc += b2f(v.x >> 16)     * wp[1];
  acc += b2f(v.y & 0xffffu) * wp[2];
  acc += b2f(v.y >> 16)     * wp[3];
  acc += b2f(v.z & 0xffffu) * wp[4];
  acc += b2f(v.z >> 16)     * wp[5];
  acc += b2f(v.w & 0xffffu) * wp[6];
  acc += b2f(v.w >> 16)     * wp[7];
#pragma unroll
  for (int m = 16; m >= 1; m >>= 1) acc += __shfl_xor(acc, m, 64);
  if (l == 0) out[g] = acc + bptr[0];
}

// ---------------- launcher ----------------

extern "C" void kernel_launch(void* const* d_in, const int* in_sizes, int n_in,
                              void* d_out, int out_size, void* d_ws, size_t ws_size,
                              hipStream_t stream)
{
  const float* x_thesis = (const float*)d_in[0];
  const int*   mentor_id = (const int*)d_in[1];
  const int*   esrc = (const int*)d_in[2];
  const int*   edst = (const int*)d_in[3];
  const int*   qsrc = (const int*)d_in[4];
  const int*   qdst = (const int*)d_in[5];
  const float* lin_w = (const float*)d_in[6];
  const float* lin_b = (const float*)d_in[7];
  const float* prof  = (const float*)d_in[8];
  const float* Wn_sup = (const float*)d_in[9];
  const float* Wr_sup = (const float*)d_in[10];
  const float* b_sup  = (const float*)d_in[11];
  const float* Wn_rev = (const float*)d_in[12];
  const float* Wr_rev = (const float*)d_in[13];
  const float* b_rev  = (const float*)d_in[14];
  const float* cls_w  = (const float*)d_in[15];
  const float* cls_b  = (const float*)d_in[16];

  const int NT = in_sizes[0] / F_IN;
  const int NM = in_sizes[1];
  const int E  = in_sizes[2];
  const int Q  = in_sizes[4];
  const int L  = in_sizes[11] / D;

  char* wsb = (char*)d_ws;
  size_t off = 0;
  auto alloc = [&](size_t bytes) {
    void* p = wsb + off;
    off = (off + bytes + 255) & ~(size_t)255;
    return p;
  };
  unsigned short* x_bf  = (unsigned short*)alloc((size_t)NT * F_IN * 2);
  unsigned short* h_t   = (unsigned short*)alloc((size_t)NT * D * 2);
  unsigned short* a_t   = (unsigned short*)alloc((size_t)NT * D * 2);
  unsigned short* h_m   = (unsigned short*)alloc((size_t)NM * D * 2);
  unsigned short* a_m   = (unsigned short*)alloc((size_t)NM * D * 2);
  unsigned short* linw_bf = (unsigned short*)alloc((size_t)D * F_IN * 2);
  unsigned short* wns_bf  = (unsigned short*)alloc((size_t)L * D * D * 2);
  unsigned short* wrs_bf  = (unsigned short*)alloc((size_t)L * D * D * 2);
  unsigned short* wnr_bf  = (unsigned short*)alloc((size_t)L * D * D * 2);
  unsigned short* wrr_bf  = (unsigned short*)alloc((size_t)L * D * D * 2);
  float* invd_t = (float*)alloc((size_t)NT * 4);
  float* invd_m = (float*)alloc((size_t)NM * 4);
  int* cnt_t = (int*)alloc((size_t)NT * 4);
  int* cnt_m = (int*)alloc((size_t)NM * 4);
  int* cur_t = (int*)alloc((size_t)NT * 4);
  int* cur_m = (int*)alloc((size_t)NM * 4);
  int* row_t = (int*)alloc(((size_t)NT + 1) * 4);
  int* row_m = (int*)alloc(((size_t)NM + 1) * 4);
  int* csr_t = (int*)alloc((size_t)E * 4);
  int* csr_m = (int*)alloc((size_t)E * 4);
  int* bsum_t = (int*)alloc(1024 * 4);
  int* bsum_m = (int*)alloc(1024 * 4);
  (void)n_in; (void)out_size; (void)ws_size;

  hipMemsetAsync(cnt_t, 0, (size_t)NT * 4, stream);
  hipMemsetAsync(cnt_m, 0, (size_t)NM * 4, stream);
  hipMemsetAsync(cur_t, 0, (size_t)NT * 4, stream);
  hipMemsetAsync(cur_m, 0, (size_t)NM * 4, stream);

  // converts
  convert_k<<<(NT * F_IN / 8 + 255) / 256, 256, 0, stream>>>(x_thesis, x_bf, NT * F_IN / 8);
  convert_k<<<(D * F_IN / 8 + 255) / 256, 256, 0, stream>>>(lin_w, linw_bf, D * F_IN / 8);
  convert_k<<<(L * D * D / 8 + 255) / 256, 256, 0, stream>>>(Wn_sup, wns_bf, L * D * D / 8);
  convert_k<<<(L * D * D / 8 + 255) / 256, 256, 0, stream>>>(Wr_sup, wrs_bf, L * D * D / 8);
  convert_k<<<(L * D * D / 8 + 255) / 256, 256, 0, stream>>>(Wn_rev, wnr_bf, L * D * D / 8);
  convert_k<<<(L * D * D / 8 + 255) / 256, 256, 0, stream>>>(Wr_rev, wrr_bf, L * D * D / 8);
  gather_conv_k<<<(NM * 16 + 255) / 256, 256, 0, stream>>>(prof, mentor_id, h_m, NM);

  // CSR build
  int eb = (E + 255) / 256;
  count_edges_k<<<eb, 256, 0, stream>>>(esrc, cnt_t, E);
  count_edges_k<<<eb, 256, 0, stream>>>(edst, cnt_m, E);
  inv_deg_k<<<(NT + 255) / 256, 256, 0, stream>>>(cnt_t, invd_t, NT);
  inv_deg_k<<<(NM + 255) / 256, 256, 0, stream>>>(cnt_m, invd_m, NM);
  int nbt = (NT + 1023) / 1024, nbm = (NM + 1023) / 1024;
  scan1_k<<<nbt, 256, 0, stream>>>(cnt_t, bsum_t, NT);
  scan2_k<<<1, 64, 0, stream>>>(bsum_t, nbt);
  scan3_k<<<nbt, 256, 0, stream>>>(cnt_t, bsum_t, row_t, NT, E);
  scan1_k<<<nbm, 256, 0, stream>>>(cnt_m, bsum_m, NM);
  scan2_k<<<1, 64, 0, stream>>>(bsum_m, nbm);
  scan3_k<<<nbm, 256, 0, stream>>>(cnt_m, bsum_m, row_m, NM, E);
  fill_csr_k<<<eb, 256, 0, stream>>>(esrc, edst, row_t, cur_t, csr_t, E);
  fill_csr_k<<<eb, 256, 0, stream>>>(edst, esrc, row_m, cur_m, csr_m, E);

  // encoder: h_t = x @ lin_w^T + lin_b
  gemm_bf16_k<F_IN, 0, false><<<(NT + 127) / 128, 256, 0, stream>>>(
      x_bf, linw_bf, nullptr, nullptr, lin_b, h_t, NT);

  for (int l = 0; l < L; ++l) {
    aggregate_k<<<(NM + 3) / 4, 256, 0, stream>>>(h_t, row_m, csr_m, invd_m, a_m, NM);
    aggregate_k<<<(NT + 3) / 4, 256, 0, stream>>>(h_m, row_t, csr_t, invd_t, a_t, NT);

    const unsigned short* wns = wns_bf + (size_t)l * D * D;
    const unsigned short* wrs = wrs_bf + (size_t)l * D * D;
    const unsigned short* wnr = wnr_bf + (size_t)l * D * D;
    const unsigned short* wrr = wrr_bf + (size_t)l * D * D;
    const float* bs = b_sup + (size_t)l * D;
    const float* br = b_rev + (size_t)l * D;
    if (l < L - 1) {
      gemm_bf16_k<D, D, true><<<(NM + 127) / 128, 256, 0, stream>>>(a_m, wns, h_m, wrs, bs, a_m, NM);
      gemm_bf16_k<D, D, true><<<(NT + 127) / 128, 256, 0, stream>>>(a_t, wnr, h_t, wrr, br, a_t, NT);
    } else {
      gemm_bf16_k<D, D, false><<<(NM + 127) / 128, 256, 0, stream>>>(a_m, wns, h_m, wrs, bs, a_m, NM);
      gemm_bf16_k<D, D, false><<<(NT + 127) / 128, 256, 0, stream>>>(a_t, wnr, h_t, wrr, br, a_t, NT);
    }
    unsigned short* tmp;
    tmp = h_t; h_t = a_t; a_t = tmp;
    tmp = h_m; h_m = a_m; a_m = tmp;
  }

  classify_k<<<(Q + 7) / 8, 256, 0, stream>>>(h_t, h_m, qsrc, qdst, cls_w, cls_b,
                                              (float*)d_out, Q);
}

// Round 3
// 366.350 us; speedup vs baseline: 3.5891x; 1.5222x over previous
//
#include <hip/hip_runtime.h>
#include <cstdint>
#include <cstddef>

#define D 128
#define F_IN 256

typedef __attribute__((ext_vector_type(8))) short bf16x8;
typedef __attribute__((ext_vector_type(4))) float f32x4;

__device__ __forceinline__ unsigned short f2bs(float f) {
  unsigned int x = __builtin_bit_cast(unsigned int, f);
  x = x + 0x7fffu + ((x >> 16) & 1u);           // round-to-nearest-even
  return (unsigned short)(x >> 16);
}
__device__ __forceinline__ float b2f(unsigned int lo16) {
  unsigned int x = lo16 << 16;
  return __builtin_bit_cast(float, x);
}
__device__ __forceinline__ void gl_lds16(const unsigned short* g, unsigned short* l) {
  __builtin_amdgcn_global_load_lds(
      (__attribute__((address_space(1))) void*)g,
      (__attribute__((address_space(3))) void*)l, 16, 0, 0);
}

// ---------------- CSR build (merged kernels) ----------------

__global__ void count_both_k(const int* __restrict__ esrc, const int* __restrict__ edst,
                             int* __restrict__ cnt_t, int* __restrict__ cnt_m, int E) {
  int e = blockIdx.x * blockDim.x + threadIdx.x;
  if (e < E) {
    atomicAdd(&cnt_t[esrc[e]], 1);
    atomicAdd(&cnt_m[edst[e]], 1);
  }
}

__global__ void inv_both_k(const int* __restrict__ ct, float* __restrict__ it, int nt,
                           const int* __restrict__ cm, float* __restrict__ im, int nm) {
  int i = blockIdx.x * blockDim.x + threadIdx.x;
  if (i < nt) { int c = ct[i]; it[i] = 1.0f / (float)(c > 1 ? c : 1); }
  int j = i - nt;
  if (j >= 0 && j < nm) { int c = cm[j]; im[j] = 1.0f / (float)(c > 1 ? c : 1); }
}

__global__ void scan1_both_k(const int* __restrict__ cnt_t, int* __restrict__ bsum_t, int nT, int nbt,
                             const int* __restrict__ cnt_m, int* __restrict__ bsum_m, int nM) {
  const int* cnt; int* bsum; int n; int blk;
  if ((int)blockIdx.x < nbt) { cnt = cnt_t; bsum = bsum_t; n = nT; blk = blockIdx.x; }
  else { cnt = cnt_m; bsum = bsum_m; n = nM; blk = blockIdx.x - nbt; }
  __shared__ int sd[256];
  int t = threadIdx.x;
  int base = blk * 1024 + t * 4;
  int s = 0;
#pragma unroll
  for (int j = 0; j < 4; ++j) { int i = base + j; if (i < n) s += cnt[i]; }
  sd[t] = s;
  __syncthreads();
  if (t == 0) { int tot = 0; for (int i = 0; i < 256; ++i) tot += sd[i]; bsum[blk] = tot; }
}

// parallel exclusive scan of block sums (nb <= 1024), block 0 -> A, block 1 -> B
__global__ void scan2_both_k(int* __restrict__ bsA, int nA, int* __restrict__ bsB, int nB) {
  int* bs = (blockIdx.x == 0) ? bsA : bsB;
  int nb  = (blockIdx.x == 0) ? nA : nB;
  __shared__ int sd[256];
  int t = threadIdx.x;
  int base = t * 4;
  int v0 = 0, v1 = 0, v2 = 0, v3 = 0;
  if (base + 0 < nb) v0 = bs[base + 0];
  if (base + 1 < nb) v1 = bs[base + 1];
  if (base + 2 < nb) v2 = bs[base + 2];
  if (base + 3 < nb) v3 = bs[base + 3];
  int tsum = v0 + v1 + v2 + v3;
  sd[t] = tsum;
  __syncthreads();
  for (int d2 = 1; d2 < 256; d2 <<= 1) {
    int y = (t >= d2) ? sd[t - d2] : 0;
    __syncthreads();
    sd[t] += y;
    __syncthreads();
  }
  int excl = sd[t] - tsum;
  if (base + 0 < nb) { bs[base + 0] = excl; excl += v0; }
  if (base + 1 < nb) { bs[base + 1] = excl; excl += v1; }
  if (base + 2 < nb) { bs[base + 2] = excl; excl += v2; }
  if (base + 3 < nb) { bs[base + 3] = excl; excl += v3; }
}

__global__ void scan3_both_k(const int* __restrict__ cnt_t, const int* __restrict__ bsum_t,
                             int* __restrict__ row_t, int nT, int nbt, int totT,
                             const int* __restrict__ cnt_m, const int* __restrict__ bsum_m,
                             int* __restrict__ row_m, int nM, int totM) {
  const int* cnt; const int* bsum; int* row; int n; int blk; int total;
  if ((int)blockIdx.x < nbt) { cnt = cnt_t; bsum = bsum_t; row = row_t; n = nT; blk = blockIdx.x; total = totT; }
  else { cnt = cnt_m; bsum = bsum_m; row = row_m; n = nM; blk = blockIdx.x - nbt; total = totM; }
  __shared__ int sd[256];
  __shared__ int sx[256];
  int t = threadIdx.x;
  int base = blk * 1024 + t * 4;
  int s = 0;
#pragma unroll
  for (int j = 0; j < 4; ++j) { int i = base + j; if (i < n) s += cnt[i]; }
  sd[t] = s;
  __syncthreads();
  if (t == 0) {
    int run = bsum[blk];
    for (int i = 0; i < 256; ++i) { sx[i] = run; run += sd[i]; }
  }
  __syncthreads();
  int run = sx[t];
#pragma unroll
  for (int j = 0; j < 4; ++j) {
    int i = base + j;
    if (i < n) { row[i] = run; run += cnt[i]; }
  }
  if (blk == 0 && t == 0) row[n] = total;
}

__global__ void fill_both_k(const int* __restrict__ esrc, const int* __restrict__ edst,
                            const int* __restrict__ row_t, const int* __restrict__ row_m,
                            int* __restrict__ cur_t, int* __restrict__ cur_m,
                            int* __restrict__ csr_t, int* __restrict__ csr_m, int E) {
  int e = blockIdx.x * blockDim.x + threadIdx.x;
  if (e < E) {
    int s = esrc[e], d = edst[e];
    int p = atomicAdd(&cur_t[s], 1);
    csr_t[row_t[s] + p] = d;
    int q = atomicAdd(&cur_m[d], 1);
    csr_m[row_m[d] + q] = s;
  }
}

// ---------------- converts ----------------

__global__ void convert_k(const float* __restrict__ s, unsigned short* __restrict__ d, int n8) {
  int i = blockIdx.x * blockDim.x + threadIdx.x;
  if (i >= n8) return;
  const float4* sp = (const float4*)(s + (size_t)i * 8);
  float4 a = sp[0], b = sp[1];
  uint4 o;
  o.x = (unsigned)f2bs(a.x) | ((unsigned)f2bs(a.y) << 16);
  o.y = (unsigned)f2bs(a.z) | ((unsigned)f2bs(a.w) << 16);
  o.z = (unsigned)f2bs(b.x) | ((unsigned)f2bs(b.y) << 16);
  o.w = (unsigned)f2bs(b.z) | ((unsigned)f2bs(b.w) << 16);
  *(uint4*)(d + (size_t)i * 8) = o;
}

// 5 small weight tensors in one launch (sizes in 8-elem chunks)
__global__ void convert5_k(const float* __restrict__ s0, unsigned short* __restrict__ d0, int n0,
                           const float* __restrict__ s1, unsigned short* __restrict__ d1, int n1,
                           const float* __restrict__ s2, unsigned short* __restrict__ d2, int n2,
                           const float* __restrict__ s3, unsigned short* __restrict__ d3, int n3,
                           const float* __restrict__ s4, unsigned short* __restrict__ d4, int n4) {
  int j = blockIdx.x * blockDim.x + threadIdx.x;
  const float* s; unsigned short* d;
  if (j < n0) { s = s0; d = d0; }
  else {
    j -= n0;
    if (j < n1) { s = s1; d = d1; }
    else {
      j -= n1;
      if (j < n2) { s = s2; d = d2; }
      else {
        j -= n2;
        if (j < n3) { s = s3; d = d3; }
        else {
          j -= n3;
          if (j >= n4) return;
          s = s4; d = d4;
        }
      }
    }
  }
  const float4* sp = (const float4*)(s + (size_t)j * 8);
  float4 a = sp[0], b = sp[1];
  uint4 o;
  o.x = (unsigned)f2bs(a.x) | ((unsigned)f2bs(a.y) << 16);
  o.y = (unsigned)f2bs(a.z) | ((unsigned)f2bs(a.w) << 16);
  o.z = (unsigned)f2bs(b.x) | ((unsigned)f2bs(b.y) << 16);
  o.w = (unsigned)f2bs(b.z) | ((unsigned)f2bs(b.w) << 16);
  *(uint4*)(d + (size_t)j * 8) = o;
}

__global__ void gather_conv_k(const float* __restrict__ emb, const int* __restrict__ ids,
                              unsigned short* __restrict__ o, int n) {
  int i = blockIdx.x * blockDim.x + threadIdx.x;
  if (i >= n * 16) return;
  int r = i >> 4, c = (i & 15) * 8;
  const float* s = emb + (size_t)ids[r] * D + c;
  float4 a = *(const float4*)s, b = *(const float4*)(s + 4);
  uint4 v;
  v.x = (unsigned)f2bs(a.x) | ((unsigned)f2bs(a.y) << 16);
  v.y = (unsigned)f2bs(a.z) | ((unsigned)f2bs(a.w) << 16);
  v.z = (unsigned)f2bs(b.x) | ((unsigned)f2bs(b.y) << 16);
  v.w = (unsigned)f2bs(b.z) | ((unsigned)f2bs(b.w) << 16);
  *(uint4*)(o + (size_t)r * D + c) = v;
}

// ---------------- aggregation: merged both directions, deep-ILP pull ----------------
// one 64-lane wave per node; 8/4-deep unrolled gathers + predicated remainder so
// up to 16 VMEM ops are in flight before any wait.

__global__ __launch_bounds__(256) void aggregate2_k(
    const unsigned short* __restrict__ tabM, const int* __restrict__ rowpM,
    const int* __restrict__ idxM, const float* __restrict__ invdM,
    unsigned short* __restrict__ outM, int nM, int nblkM,
    const unsigned short* __restrict__ tabT, const int* __restrict__ rowpT,
    const int* __restrict__ idxT, const float* __restrict__ invdT,
    unsigned short* __restrict__ outT, int nT)
{
  const unsigned short* tab; const int* rowp; const int* idx; const float* invd;
  unsigned short* outp; int n, node;
  if ((int)blockIdx.x < nblkM) {
    tab = tabM; rowp = rowpM; idx = idxM; invd = invdM; outp = outM; n = nM;
    node = blockIdx.x * 4 + (threadIdx.x >> 6);
  } else {
    tab = tabT; rowp = rowpT; idx = idxT; invd = invdT; outp = outT; n = nT;
    node = (blockIdx.x - nblkM) * 4 + (threadIdx.x >> 6);
  }
  if (node >= n) return;
  int lane = threadIdx.x & 63;
  int b = rowp[node], e = rowp[node + 1];
  float ax = 0.f, ay = 0.f;
  int p = b;
  while (p + 8 <= e) {
    int nn[8]; unsigned vv[8];
#pragma unroll
    for (int u = 0; u < 8; ++u) nn[u] = idx[p + u];
#pragma unroll
    for (int u = 0; u < 8; ++u) vv[u] = *(const unsigned*)(tab + (size_t)nn[u] * D + lane * 2);
#pragma unroll
    for (int u = 0; u < 8; ++u) { ax += b2f(vv[u] & 0xffffu); ay += b2f(vv[u] >> 16); }
    p += 8;
  }
  if (p + 4 <= e) {
    int nn[4]; unsigned vv[4];
#pragma unroll
    for (int u = 0; u < 4; ++u) nn[u] = idx[p + u];
#pragma unroll
    for (int u = 0; u < 4; ++u) vv[u] = *(const unsigned*)(tab + (size_t)nn[u] * D + lane * 2);
#pragma unroll
    for (int u = 0; u < 4; ++u) { ax += b2f(vv[u] & 0xffffu); ay += b2f(vv[u] >> 16); }
    p += 4;
  }
  {  // remainder 0..3, predicated (wave-uniform branches), all loads independent
    bool h0 = p < e, h1 = p + 1 < e, h2 = p + 2 < e;
    int n0 = 0, n1 = 0, n2 = 0;
    unsigned w0 = 0, w1 = 0, w2 = 0;
    if (h0) n0 = idx[p];
    if (h1) n1 = idx[p + 1];
    if (h2) n2 = idx[p + 2];
    if (h0) w0 = *(const unsigned*)(tab + (size_t)n0 * D + lane * 2);
    if (h1) w1 = *(const unsigned*)(tab + (size_t)n1 * D + lane * 2);
    if (h2) w2 = *(const unsigned*)(tab + (size_t)n2 * D + lane * 2);
    if (h0) { ax += b2f(w0 & 0xffffu); ay += b2f(w0 >> 16); }
    if (h1) { ax += b2f(w1 & 0xffffu); ay += b2f(w1 >> 16); }
    if (h2) { ax += b2f(w2 & 0xffffu); ay += b2f(w2 >> 16); }
  }
  float s = invd[node];
  unsigned o = (unsigned)f2bs(ax * s) | ((unsigned)f2bs(ay * s) << 16);
  *(unsigned*)(outp + (size_t)node * D + lane * 2) = o;
}

// ---------------- bf16 MFMA fused dual GEMM ----------------

template<int K1, int K2, bool RELU>
__device__ __forceinline__ void gemm_body(
    const unsigned short* __restrict__ A, const unsigned short* __restrict__ WA,
    const unsigned short* __restrict__ B, const unsigned short* __restrict__ WB,
    const float* __restrict__ bias, unsigned short* __restrict__ out, int M,
    int blk, unsigned short* sm)   // sm: 16384 ushorts (32KB)
{
  unsigned short* smA = sm;           // 128x32 bf16
  unsigned short* smW = sm + 4096;    // 128x32 bf16

  const int tid = threadIdx.x;
  const int w  = tid >> 6;
  const int l  = tid & 63;
  const int wr = w >> 1, wc = w & 1;
  const int lr = l & 15, kg = l >> 4;
  const int row0 = blk * 128;
  const int srow = l >> 2;
  const int skk  = (l & 3) * 8;

  f32x4 acc[4][4] = {};

  constexpr int NK1 = K1 / 32;
  constexpr int NK2 = (K2 > 0) ? (K2 / 32) : 0;

#pragma unroll 1
  for (int st = 0; st < NK1 + NK2; ++st) {
    const unsigned short* Ap; const unsigned short* Wp; int K; int k0;
    if (st < NK1) { Ap = A; Wp = WA; K = K1; k0 = st * 32; }
    else          { Ap = B; Wp = WB; K = K2; k0 = (st - NK1) * 32; }
    if (st) __syncthreads();
#pragma unroll
    for (int q = 0; q < 2; ++q) {
      int c = w * 2 + q;
      int r = c * 16 + srow;
      int gr = row0 + r;
      if (gr < M) gl_lds16(Ap + (size_t)gr * K + k0 + skk, &smA[c * 512 + l * 8]);
      gl_lds16(Wp + (size_t)r * K + k0 + skk, &smW[c * 512 + l * 8]);
    }
    __syncthreads();
    bf16x8 aF[4], bF[4];
#pragma unroll
    for (int i = 0; i < 4; ++i)
      aF[i] = *(const bf16x8*)&smA[(wr * 64 + i * 16 + lr) * 32 + kg * 8];
#pragma unroll
    for (int j = 0; j < 4; ++j)
      bF[j] = *(const bf16x8*)&smW[(wc * 64 + j * 16 + lr) * 32 + kg * 8];
#pragma unroll
    for (int i = 0; i < 4; ++i)
#pragma unroll
      for (int j = 0; j < 4; ++j)
        acc[i][j] = __builtin_amdgcn_mfma_f32_16x16x32_bf16(aF[i], bF[j], acc[i][j], 0, 0, 0);
  }

  __syncthreads();
  float bn[4];
#pragma unroll
  for (int j = 0; j < 4; ++j) bn[j] = bias[wc * 64 + j * 16 + lr];
  unsigned short* ow = sm + w * 4096;
#pragma unroll
  for (int i = 0; i < 4; ++i)
#pragma unroll
    for (int j = 0; j < 4; ++j) {
      f32x4 v = acc[i][j];
#pragma unroll
      for (int r = 0; r < 4; ++r) {
        float x = v[r] + bn[j];
        if (RELU) x = fmaxf(x, 0.f);
        ow[(i * 16 + kg * 4 + r) * 64 + j * 16 + lr] = f2bs(x);
      }
    }
  __syncthreads();
#pragma unroll
  for (int q = 0; q < 8; ++q) {
    int u = q * 64 + l;
    int lrow = u >> 3;
    int cu = (u & 7) * 8;
    int gr = row0 + wr * 64 + lrow;
    if (gr < M)
      *(uint4*)(out + (size_t)gr * D + wc * 64 + cu) = *(const uint4*)&ow[lrow * 64 + cu];
  }
}

template<int K1, int K2, bool RELU>
__global__ __launch_bounds__(256) void gemm_one_k(
    const unsigned short* __restrict__ A, const unsigned short* __restrict__ WA,
    const unsigned short* __restrict__ B, const unsigned short* __restrict__ WB,
    const float* __restrict__ bias, unsigned short* __restrict__ out, int M)
{
  __shared__ unsigned short sm[16384];
  gemm_body<K1, K2, RELU>(A, WA, B, WB, bias, out, M, blockIdx.x, sm);
}

// both per-layer GEMMs (mentor + thesis) in one dispatch
template<bool RELU>
__global__ __launch_bounds__(256) void gemm_pair_k(
    const unsigned short* __restrict__ Am, const unsigned short* __restrict__ WAm,
    const unsigned short* __restrict__ Bm, const unsigned short* __restrict__ WBm,
    const float* __restrict__ biasm, unsigned short* __restrict__ outm, int Mm, int nbm,
    const unsigned short* __restrict__ At, const unsigned short* __restrict__ WAt,
    const unsigned short* __restrict__ Bt, const unsigned short* __restrict__ WBt,
    const float* __restrict__ biast, unsigned short* __restrict__ outt, int Mt)
{
  __shared__ unsigned short sm[16384];
  if ((int)blockIdx.x < nbm)
    gemm_body<D, D, RELU>(Am, WAm, Bm, WBm, biasm, outm, Mm, blockIdx.x, sm);
  else
    gemm_body<D, D, RELU>(At, WAt, Bt, WBt, biast, outt, Mt, blockIdx.x - nbm, sm);
}

// ---------------- classifier ----------------

__global__ __launch_bounds__(256) void classify_k(
    const unsigned short* __restrict__ ht, const unsigned short* __restrict__ hm,
    const int* __restrict__ qs, const int* __restrict__ qd,
    const float* __restrict__ w, const float* __restrict__ bptr,
    float* __restrict__ out, int Q)
{
  int g = blockIdx.x * 8 + (threadIdx.x >> 5);
  if (g >= Q) return;
  int l = threadIdx.x & 31;
  const unsigned short* src = (l < 16)
      ? ht + (size_t)qs[g] * D + l * 8
      : hm + (size_t)qd[g] * D + (l - 16) * 8;
  uint4 v = *(const uint4*)src;
  const float* wp = w + l * 8;
  float acc = 0.f;
  acc += b2f(v.x & 0xffffu) * wp[0];
  acc += b2f(v.x >> 16)     * wp[1];
  acc += b2f(v.y & 0xffffu) * wp[2];
  acc += b2f(v.y >> 16)     * wp[3];
  acc += b2f(v.z & 0xffffu) * wp[4];
  acc += b2f(v.z >> 16)     * wp[5];
  acc += b2f(v.w & 0xffffu) * wp[6];
  acc += b2f(v.w >> 16)     * wp[7];
#pragma unroll
  for (int m = 16; m >= 1; m >>= 1) acc += __shfl_xor(acc, m, 64);
  if (l == 0) out[g] = acc + bptr[0];
}

// ---------------- launcher ----------------

extern "C" void kernel_launch(void* const* d_in, const int* in_sizes, int n_in,
                              void* d_out, int out_size, void* d_ws, size_t ws_size,
                              hipStream_t stream)
{
  const float* x_thesis = (const float*)d_in[0];
  const int*   mentor_id = (const int*)d_in[1];
  const int*   esrc = (const int*)d_in[2];
  const int*   edst = (const int*)d_in[3];
  const int*   qsrc = (const int*)d_in[4];
  const int*   qdst = (const int*)d_in[5];
  const float* lin_w = (const float*)d_in[6];
  const float* lin_b = (const float*)d_in[7];
  const float* prof  = (const float*)d_in[8];
  const float* Wn_sup = (const float*)d_in[9];
  const float* Wr_sup = (const float*)d_in[10];
  const float* b_sup  = (const float*)d_in[11];
  const float* Wn_rev = (const float*)d_in[12];
  const float* Wr_rev = (const float*)d_in[13];
  const float* b_rev  = (const float*)d_in[14];
  const float* cls_w  = (const float*)d_in[15];
  const float* cls_b  = (const float*)d_in[16];

  const int NT = in_sizes[0] / F_IN;
  const int NM = in_sizes[1];
  const int E  = in_sizes[2];
  const int Q  = in_sizes[4];
  const int L  = in_sizes[11] / D;

  char* wsb = (char*)d_ws;
  size_t off = 0;
  auto alloc = [&](size_t bytes) {
    void* p = wsb + off;
    off = (off + bytes + 255) & ~(size_t)255;
    return p;
  };
  unsigned short* x_bf  = (unsigned short*)alloc((size_t)NT * F_IN * 2);
  unsigned short* h_t   = (unsigned short*)alloc((size_t)NT * D * 2);
  unsigned short* a_t   = (unsigned short*)alloc((size_t)NT * D * 2);
  unsigned short* h_m   = (unsigned short*)alloc((size_t)NM * D * 2);
  unsigned short* a_m   = (unsigned short*)alloc((size_t)NM * D * 2);
  unsigned short* linw_bf = (unsigned short*)alloc((size_t)D * F_IN * 2);
  unsigned short* wns_bf  = (unsigned short*)alloc((size_t)L * D * D * 2);
  unsigned short* wrs_bf  = (unsigned short*)alloc((size_t)L * D * D * 2);
  unsigned short* wnr_bf  = (unsigned short*)alloc((size_t)L * D * D * 2);
  unsigned short* wrr_bf  = (unsigned short*)alloc((size_t)L * D * D * 2);
  float* invd_t = (float*)alloc((size_t)NT * 4);
  float* invd_m = (float*)alloc((size_t)NM * 4);
  size_t cnt_off = off;
  int* cnt_t = (int*)alloc((size_t)NT * 4);
  int* cnt_m = (int*)alloc((size_t)NM * 4);
  int* cur_t = (int*)alloc((size_t)NT * 4);
  int* cur_m = (int*)alloc((size_t)NM * 4);
  size_t cnt_end = off;
  int* row_t = (int*)alloc(((size_t)NT + 1) * 4);
  int* row_m = (int*)alloc(((size_t)NM + 1) * 4);
  int* csr_t = (int*)alloc((size_t)E * 4);
  int* csr_m = (int*)alloc((size_t)E * 4);
  int* bsum_t = (int*)alloc(1024 * 4);
  int* bsum_m = (int*)alloc(1024 * 4);
  (void)n_in; (void)out_size; (void)ws_size;

  // zero all four counter arrays with one memset (contiguous region)
  hipMemsetAsync(wsb + cnt_off, 0, cnt_end - cnt_off, stream);

  // converts
  convert_k<<<(NT * F_IN / 8 + 255) / 256, 256, 0, stream>>>(x_thesis, x_bf, NT * F_IN / 8);
  {
    int n0 = D * F_IN / 8, nw = L * D * D / 8;
    int tot = n0 + 4 * nw;
    convert5_k<<<(tot + 255) / 256, 256, 0, stream>>>(
        lin_w, linw_bf, n0, Wn_sup, wns_bf, nw, Wr_sup, wrs_bf, nw,
        Wn_rev, wnr_bf, nw, Wr_rev, wrr_bf, nw);
  }
  gather_conv_k<<<(NM * 16 + 255) / 256, 256, 0, stream>>>(prof, mentor_id, h_m, NM);

  // CSR build
  int eb = (E + 255) / 256;
  count_both_k<<<eb, 256, 0, stream>>>(esrc, edst, cnt_t, cnt_m, E);
  inv_both_k<<<(NT + NM + 255) / 256, 256, 0, stream>>>(cnt_t, invd_t, NT, cnt_m, invd_m, NM);
  int nbt = (NT + 1023) / 1024, nbm = (NM + 1023) / 1024;
  scan1_both_k<<<nbt + nbm, 256, 0, stream>>>(cnt_t, bsum_t, NT, nbt, cnt_m, bsum_m, NM);
  scan2_both_k<<<2, 256, 0, stream>>>(bsum_t, nbt, bsum_m, nbm);
  scan3_both_k<<<nbt + nbm, 256, 0, stream>>>(cnt_t, bsum_t, row_t, NT, nbt, E,
                                              cnt_m, bsum_m, row_m, NM, E);
  fill_both_k<<<eb, 256, 0, stream>>>(esrc, edst, row_t, row_m, cur_t, cur_m, csr_t, csr_m, E);

  // encoder: h_t = x @ lin_w^T + lin_b
  gemm_one_k<F_IN, 0, false><<<(NT + 127) / 128, 256, 0, stream>>>(
      x_bf, linw_bf, nullptr, nullptr, lin_b, h_t, NT);

  int agg_nbm = (NM + 3) / 4, agg_nbt = (NT + 3) / 4;
  int gem_nbm = (NM + 127) / 128, gem_nbt = (NT + 127) / 128;
  for (int l = 0; l < L; ++l) {
    aggregate2_k<<<agg_nbm + agg_nbt, 256, 0, stream>>>(
        h_t, row_m, csr_m, invd_m, a_m, NM, agg_nbm,
        h_m, row_t, csr_t, invd_t, a_t, NT);

    const unsigned short* wns = wns_bf + (size_t)l * D * D;
    const unsigned short* wrs = wrs_bf + (size_t)l * D * D;
    const unsigned short* wnr = wnr_bf + (size_t)l * D * D;
    const unsigned short* wrr = wrr_bf + (size_t)l * D * D;
    const float* bs = b_sup + (size_t)l * D;
    const float* br = b_rev + (size_t)l * D;
    if (l < L - 1) {
      gemm_pair_k<true><<<gem_nbm + gem_nbt, 256, 0, stream>>>(
          a_m, wns, h_m, wrs, bs, a_m, NM, gem_nbm,
          a_t, wnr, h_t, wrr, br, a_t, NT);
    } else {
      gemm_pair_k<false><<<gem_nbm + gem_nbt, 256, 0, stream>>>(
          a_m, wns, h_m, wrs, bs, a_m, NM, gem_nbm,
          a_t, wnr, h_t, wrr, br, a_t, NT);
    }
    unsigned short* tmp;
    tmp = h_t; h_t = a_t; a_t = tmp;
    tmp = h_m; h_m = a_m; a_m = tmp;
  }

  classify_k<<<(Q + 7) / 8, 256, 0, stream>>>(h_t, h_m, qsrc, qdst, cls_w, cls_b,
                                              (float*)d_out, Q);
}

// Round 4
// 298.983 us; speedup vs baseline: 4.3979x; 1.2253x over previous
//
#include <hip/hip_runtime.h>
#include <cstdint>
#include <cstddef>

#define D 128
#define F_IN 256

typedef __attribute__((ext_vector_type(8))) short bf16x8;
typedef __attribute__((ext_vector_type(4))) float f32x4;

__device__ __forceinline__ unsigned short f2bs(float f) {
  unsigned int x = __builtin_bit_cast(unsigned int, f);
  x = x + 0x7fffu + ((x >> 16) & 1u);           // round-to-nearest-even
  return (unsigned short)(x >> 16);
}
__device__ __forceinline__ float b2f(unsigned int lo16) {
  unsigned int x = lo16 << 16;
  return __builtin_bit_cast(float, x);
}
__device__ __forceinline__ void gl_lds16(const unsigned short* g, unsigned short* l) {
  __builtin_amdgcn_global_load_lds(
      (__attribute__((address_space(1))) void*)g,
      (__attribute__((address_space(3))) void*)l, 16, 0, 0);
}
__device__ __forceinline__ uint4 pack8(float4 a, float4 b) {
  uint4 o;
  o.x = (unsigned)f2bs(a.x) | ((unsigned)f2bs(a.y) << 16);
  o.y = (unsigned)f2bs(a.z) | ((unsigned)f2bs(a.w) << 16);
  o.z = (unsigned)f2bs(b.x) | ((unsigned)f2bs(b.y) << 16);
  o.w = (unsigned)f2bs(b.z) | ((unsigned)f2bs(b.w) << 16);
  return o;
}

// ================= prep: weight converts + prof gather + bucket histogram =================
// block ranges: [0,nbC) convert5, [nbC,nbC+nbG) gather_conv, rest: edge bucket histogram

__global__ __launch_bounds__(256) void prep_k(
    // convert5
    const float* __restrict__ s0, unsigned short* __restrict__ d0, int n0,
    const float* __restrict__ s1, unsigned short* __restrict__ d1, int n1,
    const float* __restrict__ s2, unsigned short* __restrict__ d2, int n2,
    const float* __restrict__ s3, unsigned short* __restrict__ d3, int n3,
    const float* __restrict__ s4, unsigned short* __restrict__ d4, int n4,
    int nbC,
    // gather
    const float* __restrict__ emb, const int* __restrict__ ids,
    unsigned short* __restrict__ hm, int NM, int nbG,
    // histogram
    const int* __restrict__ esrc, const int* __restrict__ edst,
    int* __restrict__ bktT, int* __restrict__ bktM,
    int E, int SHT, int SHM, int nbA)
{
  int bid = blockIdx.x;
  int tid = threadIdx.x;
  if (bid < nbC) {
    int j = bid * 256 + tid;
    const float* s; unsigned short* d;
    if (j < n0) { s = s0; d = d0; }
    else {
      j -= n0;
      if (j < n1) { s = s1; d = d1; }
      else {
        j -= n1;
        if (j < n2) { s = s2; d = d2; }
        else {
          j -= n2;
          if (j < n3) { s = s3; d = d3; }
          else { j -= n3; if (j >= n4) return; s = s4; d = d4; }
        }
      }
    }
    const float4* sp = (const float4*)(s + (size_t)j * 8);
    *(uint4*)(d + (size_t)j * 8) = pack8(sp[0], sp[1]);
    return;
  }
  bid -= nbC;
  if (bid < nbG) {
    int i = bid * 256 + tid;
    if (i >= NM * 16) return;
    int r = i >> 4, c = (i & 15) * 8;
    const float* s = emb + (size_t)ids[r] * D + c;
    *(uint4*)(hm + (size_t)r * D + c) = pack8(*(const float4*)s, *(const float4*)(s + 4));
    return;
  }
  bid -= nbG;
  // histogram
  __shared__ int sh[256];
  sh[tid] = 0;
  __syncthreads();
  int stride = nbA * 256;
  for (int e = bid * 256 + tid; e < E; e += stride) {
    atomicAdd(&sh[esrc[e] >> SHT], 1);
    atomicAdd(&sh[128 + (edst[e] >> SHM)], 1);
  }
  __syncthreads();
  if (tid < 128) { if (sh[tid]) atomicAdd(&bktT[tid], sh[tid]); }
  else { if (sh[tid]) atomicAdd(&bktM[tid - 128], sh[tid]); }
}

// ================= A2: scan bucket counts -> bases + cursors =================

__global__ void a2_scan_k(const int* __restrict__ bktT, int* __restrict__ baseT, int* __restrict__ curT, int BT,
                          const int* __restrict__ bktM, int* __restrict__ baseM, int* __restrict__ curM, int BM) {
  __shared__ int sT[129], sM[129];
  int tid = threadIdx.x;
  if (tid < BT) sT[tid] = bktT[tid];
  if (tid < BM) sM[tid] = bktM[tid];
  __syncthreads();
  if (tid == 0) { int r = 0; for (int i = 0; i < BT; ++i) { int c = sT[i]; sT[i] = r; r += c; } sT[BT] = r; }
  if (tid == 1) { int r = 0; for (int i = 0; i < BM; ++i) { int c = sM[i]; sM[i] = r; r += c; } sM[BM] = r; }
  __syncthreads();
  if (tid <= BT) { baseT[tid] = sT[tid]; if (tid < BT) curT[tid] = sT[tid]; }
  if (tid <= BM) { baseM[tid] = sM[tid]; if (tid < BM) curM[tid] = sM[tid]; }
}

// ================= A3: multi-split partition with LDS staging (coalesced writes) =================

#define CH 4096

__global__ __launch_bounds__(256) void a3_part_k(
    const int* __restrict__ esrc, const int* __restrict__ edst,
    unsigned* __restrict__ partT, unsigned* __restrict__ partM,
    int* __restrict__ curT, int* __restrict__ curM,
    int E, int BT, int BM, int SHT, int SHM)
{
  __shared__ unsigned stT[CH], stM[CH];
  __shared__ int hT[128], lbT[128], lcT[128], gbT[128];
  __shared__ int hM[128], lbM[128], lcM[128], gbM[128];
  __shared__ int st2[256];
  int tid = threadIdx.x;
  int c0 = blockIdx.x * CH;
  int len = E - c0; if (len > CH) len = CH;

  if (tid < 128) { hT[tid] = 0; hM[tid] = 0; }
  __syncthreads();
  for (int i = tid; i < len; i += 256) {
    atomicAdd(&hT[esrc[c0 + i] >> SHT], 1);
    atomicAdd(&hM[edst[c0 + i] >> SHM], 1);
  }
  __syncthreads();
  // scan both 128-halves in parallel (hT in lanes 0-127, hM in 128-255)
  int own = (tid < 128) ? hT[tid] : hM[tid - 128];
  st2[tid] = own;
  __syncthreads();
  for (int dd = 1; dd < 128; dd <<= 1) {
    int y = ((tid & 127) >= dd) ? st2[tid - dd] : 0;
    __syncthreads();
    st2[tid] += y;
    __syncthreads();
  }
  int excl = st2[tid] - own;
  if (tid < 128) { lbT[tid] = excl; lcT[tid] = excl; }
  else { lbM[tid - 128] = excl; lcM[tid - 128] = excl; }
  __syncthreads();
  // reserve global chunks
  if (tid < BT) { if (hT[tid]) gbT[tid] = atomicAdd(&curT[tid], hT[tid]); }
  if (tid >= 128 && tid - 128 < BM) { int m = tid - 128; if (hM[m]) gbM[m] = atomicAdd(&curM[m], hM[m]); }
  __syncthreads();
  // place into LDS staging
  for (int i = tid; i < len; i += 256) {
    unsigned s = (unsigned)esrc[c0 + i], dn = (unsigned)edst[c0 + i];
    int p = atomicAdd(&lcT[s >> SHT], 1);
    stT[p] = (s << 15) | dn;
    int q = atomicAdd(&lcM[dn >> SHM], 1);
    stM[q] = (dn << 17) | s;
  }
  __syncthreads();
  // coalesced copy-out per bucket
  for (int b = 0; b < BT; ++b) {
    int cb = hT[b]; if (!cb) continue;
    int lb = lbT[b]; int gb = gbT[b];
    for (int i = tid; i < cb; i += 256) partT[gb + i] = stT[lb + i];
  }
  for (int b = 0; b < BM; ++b) {
    int cb = hM[b]; if (!cb) continue;
    int lb = lbM[b]; int gb = gbM[b];
    for (int i = tid; i < cb; i += 256) partM[gb + i] = stM[lb + i];
  }
}

// ================= B: per-bucket CSR finalize (rowptr, invd, csr) =================

#define BCAP 12288

__global__ __launch_bounds__(256) void b_csr_k(
    const unsigned* __restrict__ partT, const int* __restrict__ baseT,
    int* __restrict__ rowT, float* __restrict__ invdT, int* __restrict__ csrT,
    int NT, int BT, int SHT,
    const unsigned* __restrict__ partM, const int* __restrict__ baseM,
    int* __restrict__ rowM, float* __restrict__ invdM, int* __restrict__ csrM,
    int NM, int BM, int SHM, int E)
{
  __shared__ int cnt[1024];
  __shared__ int st[256];
  __shared__ unsigned stage[BCAP];

  const unsigned* part; const int* base; int* row; float* invd; int* csr;
  int N, SH, KS; unsigned PM; int b; bool last;
  if ((int)blockIdx.x < BT) {
    part = partT; base = baseT; row = rowT; invd = invdT; csr = csrT;
    N = NT; SH = SHT; KS = 15; PM = 0x7fffu; b = blockIdx.x; last = (b == BT - 1);
  } else {
    part = partM; base = baseM; row = rowM; invd = invdM; csr = csrM;
    N = NM; SH = SHM; KS = 17; PM = 0x1ffffu; b = blockIdx.x - BT; last = (b == BM - 1);
  }
  int tid = threadIdx.x;
  int ebeg = base[b], eend = base[b + 1];
  int tot = eend - ebeg;
  int n0 = b << SH;
  int width = 1 << SH;
  int nw = N - n0; if (nw > width) nw = width;
  int seg = (width + 255) >> 8;

  for (int j = 0; j < seg; ++j) { int idx = tid * seg + j; if (idx < nw) cnt[idx] = 0; }
  __syncthreads();
  for (int i = tid; i < tot; i += 256) {
    int k = (int)(part[ebeg + i] >> KS) - n0;
    atomicAdd(&cnt[k], 1);
  }
  __syncthreads();
  // scan per-node counts
  int s = 0;
  for (int j = 0; j < seg; ++j) { int idx = tid * seg + j; if (idx < nw) s += cnt[idx]; }
  st[tid] = s;
  __syncthreads();
  for (int dd = 1; dd < 256; dd <<= 1) {
    int y = (tid >= dd) ? st[tid - dd] : 0;
    __syncthreads();
    st[tid] += y;
    __syncthreads();
  }
  int run = st[tid] - s;
  for (int j = 0; j < seg; ++j) {
    int idx = tid * seg + j;
    if (idx < nw) {
      int c = cnt[idx];
      row[n0 + idx] = ebeg + run;
      invd[n0 + idx] = 1.0f / (float)(c > 1 ? c : 1);
      cnt[idx] = run;          // becomes cursor
      run += c;
    }
  }
  if (last && tid == 0) row[N] = E;
  __syncthreads();
  if (tot <= BCAP) {
    for (int i = tid; i < tot; i += 256) {
      unsigned p = part[ebeg + i];
      int k = (int)(p >> KS) - n0;
      int pos = atomicAdd(&cnt[k], 1);
      stage[pos] = p & PM;
    }
    __syncthreads();
    for (int i = tid; i < tot; i += 256) csr[ebeg + i] = (int)stage[i];
  } else {
    for (int i = tid; i < tot; i += 256) {   // fallback, never expected
      unsigned p = part[ebeg + i];
      int k = (int)(p >> KS) - n0;
      int pos = atomicAdd(&cnt[k], 1);
      csr[ebeg + pos] = (int)(p & PM);
    }
  }
}

// ================= aggregation: merged both directions, deep-ILP pull =================

__global__ __launch_bounds__(256) void aggregate2_k(
    const unsigned short* __restrict__ tabM, const int* __restrict__ rowpM,
    const int* __restrict__ idxM, const float* __restrict__ invdM,
    unsigned short* __restrict__ outM, int nM, int nblkM,
    const unsigned short* __restrict__ tabT, const int* __restrict__ rowpT,
    const int* __restrict__ idxT, const float* __restrict__ invdT,
    unsigned short* __restrict__ outT, int nT)
{
  const unsigned short* tab; const int* rowp; const int* idx; const float* invd;
  unsigned short* outp; int n, node;
  if ((int)blockIdx.x < nblkM) {
    tab = tabM; rowp = rowpM; idx = idxM; invd = invdM; outp = outM; n = nM;
    node = blockIdx.x * 4 + (threadIdx.x >> 6);
  } else {
    tab = tabT; rowp = rowpT; idx = idxT; invd = invdT; outp = outT; n = nT;
    node = (blockIdx.x - nblkM) * 4 + (threadIdx.x >> 6);
  }
  if (node >= n) return;
  int lane = threadIdx.x & 63;
  int b = rowp[node], e = rowp[node + 1];
  float ax = 0.f, ay = 0.f;
  int p = b;
  while (p + 8 <= e) {
    int nn[8]; unsigned vv[8];
#pragma unroll
    for (int u = 0; u < 8; ++u) nn[u] = idx[p + u];
#pragma unroll
    for (int u = 0; u < 8; ++u) vv[u] = *(const unsigned*)(tab + (size_t)nn[u] * D + lane * 2);
#pragma unroll
    for (int u = 0; u < 8; ++u) { ax += b2f(vv[u] & 0xffffu); ay += b2f(vv[u] >> 16); }
    p += 8;
  }
  if (p + 4 <= e) {
    int nn[4]; unsigned vv[4];
#pragma unroll
    for (int u = 0; u < 4; ++u) nn[u] = idx[p + u];
#pragma unroll
    for (int u = 0; u < 4; ++u) vv[u] = *(const unsigned*)(tab + (size_t)nn[u] * D + lane * 2);
#pragma unroll
    for (int u = 0; u < 4; ++u) { ax += b2f(vv[u] & 0xffffu); ay += b2f(vv[u] >> 16); }
    p += 4;
  }
  {
    bool h0 = p < e, h1 = p + 1 < e, h2 = p + 2 < e;
    int n0 = 0, n1 = 0, n2 = 0;
    unsigned w0 = 0, w1 = 0, w2 = 0;
    if (h0) n0 = idx[p];
    if (h1) n1 = idx[p + 1];
    if (h2) n2 = idx[p + 2];
    if (h0) w0 = *(const unsigned*)(tab + (size_t)n0 * D + lane * 2);
    if (h1) w1 = *(const unsigned*)(tab + (size_t)n1 * D + lane * 2);
    if (h2) w2 = *(const unsigned*)(tab + (size_t)n2 * D + lane * 2);
    if (h0) { ax += b2f(w0 & 0xffffu); ay += b2f(w0 >> 16); }
    if (h1) { ax += b2f(w1 & 0xffffu); ay += b2f(w1 >> 16); }
    if (h2) { ax += b2f(w2 & 0xffffu); ay += b2f(w2 >> 16); }
  }
  float sc = invd[node];
  unsigned o = (unsigned)f2bs(ax * sc) | ((unsigned)f2bs(ay * sc) << 16);
  *(unsigned*)(outp + (size_t)node * D + lane * 2) = o;
}

// ================= bf16 MFMA fused dual GEMM =================

template<int K1, int K2, bool RELU>
__device__ __forceinline__ void gemm_body(
    const unsigned short* __restrict__ A, const unsigned short* __restrict__ WA,
    const unsigned short* __restrict__ B, const unsigned short* __restrict__ WB,
    const float* __restrict__ bias, unsigned short* __restrict__ out, int M,
    int blk, unsigned short* sm)
{
  unsigned short* smA = sm;
  unsigned short* smW = sm + 4096;

  const int tid = threadIdx.x;
  const int w  = tid >> 6;
  const int l  = tid & 63;
  const int wr = w >> 1, wc = w & 1;
  const int lr = l & 15, kg = l >> 4;
  const int row0 = blk * 128;
  const int srow = l >> 2;
  const int skk  = (l & 3) * 8;

  f32x4 acc[4][4] = {};

  constexpr int NK1 = K1 / 32;
  constexpr int NK2 = (K2 > 0) ? (K2 / 32) : 0;

#pragma unroll 1
  for (int st = 0; st < NK1 + NK2; ++st) {
    const unsigned short* Ap; const unsigned short* Wp; int K; int k0;
    if (st < NK1) { Ap = A; Wp = WA; K = K1; k0 = st * 32; }
    else          { Ap = B; Wp = WB; K = K2; k0 = (st - NK1) * 32; }
    if (st) __syncthreads();
#pragma unroll
    for (int q = 0; q < 2; ++q) {
      int c = w * 2 + q;
      int r = c * 16 + srow;
      int gr = row0 + r;
      if (gr < M) gl_lds16(Ap + (size_t)gr * K + k0 + skk, &smA[c * 512 + l * 8]);
      gl_lds16(Wp + (size_t)r * K + k0 + skk, &smW[c * 512 + l * 8]);
    }
    __syncthreads();
    bf16x8 aF[4], bF[4];
#pragma unroll
    for (int i = 0; i < 4; ++i)
      aF[i] = *(const bf16x8*)&smA[(wr * 64 + i * 16 + lr) * 32 + kg * 8];
#pragma unroll
    for (int j = 0; j < 4; ++j)
      bF[j] = *(const bf16x8*)&smW[(wc * 64 + j * 16 + lr) * 32 + kg * 8];
#pragma unroll
    for (int i = 0; i < 4; ++i)
#pragma unroll
      for (int j = 0; j < 4; ++j)
        acc[i][j] = __builtin_amdgcn_mfma_f32_16x16x32_bf16(aF[i], bF[j], acc[i][j], 0, 0, 0);
  }

  __syncthreads();
  float bn[4];
#pragma unroll
  for (int j = 0; j < 4; ++j) bn[j] = bias[wc * 64 + j * 16 + lr];
  unsigned short* ow = sm + w * 4096;
#pragma unroll
  for (int i = 0; i < 4; ++i)
#pragma unroll
    for (int j = 0; j < 4; ++j) {
      f32x4 v = acc[i][j];
#pragma unroll
      for (int r = 0; r < 4; ++r) {
        float x = v[r] + bn[j];
        if (RELU) x = fmaxf(x, 0.f);
        ow[(i * 16 + kg * 4 + r) * 64 + j * 16 + lr] = f2bs(x);
      }
    }
  __syncthreads();
#pragma unroll
  for (int q = 0; q < 8; ++q) {
    int u = q * 64 + l;
    int lrow = u >> 3;
    int cu = (u & 7) * 8;
    int gr = row0 + wr * 64 + lrow;
    if (gr < M)
      *(uint4*)(out + (size_t)gr * D + wc * 64 + cu) = *(const uint4*)&ow[lrow * 64 + cu];
  }
}

template<bool RELU>
__global__ __launch_bounds__(256) void gemm_pair_k(
    const unsigned short* __restrict__ Am, const unsigned short* __restrict__ WAm,
    const unsigned short* __restrict__ Bm, const unsigned short* __restrict__ WBm,
    const float* __restrict__ biasm, unsigned short* __restrict__ outm, int Mm, int nbm,
    const unsigned short* __restrict__ At, const unsigned short* __restrict__ WAt,
    const unsigned short* __restrict__ Bt, const unsigned short* __restrict__ WBt,
    const float* __restrict__ biast, unsigned short* __restrict__ outt, int Mt)
{
  __shared__ unsigned short sm[16384];
  if ((int)blockIdx.x < nbm)
    gemm_body<D, D, RELU>(Am, WAm, Bm, WBm, biasm, outm, Mm, blockIdx.x, sm);
  else
    gemm_body<D, D, RELU>(At, WAt, Bt, WBt, biast, outt, Mt, blockIdx.x - nbm, sm);
}

// encoder GEMM: A is fp32 (converted in-kernel during staging), W bf16, K=256
__global__ __launch_bounds__(256) void gemm_enc_k(
    const float* __restrict__ A, const unsigned short* __restrict__ W,
    const float* __restrict__ bias, unsigned short* __restrict__ out, int M)
{
  __shared__ unsigned short sm[16384];
  unsigned short* smA = sm;
  unsigned short* smW = sm + 4096;

  const int tid = threadIdx.x;
  const int w  = tid >> 6;
  const int l  = tid & 63;
  const int wr = w >> 1, wc = w & 1;
  const int lr = l & 15, kg = l >> 4;
  const int row0 = blockIdx.x * 128;

  f32x4 acc[4][4] = {};

#pragma unroll 1
  for (int st = 0; st < F_IN / 32; ++st) {
    int k0 = st * 32;
    if (st) __syncthreads();
    {
      // stage A: 128 rows x 32 fp32 -> bf16; thread t does row t>>1, 16 cols
      int r = tid >> 1, ch = tid & 1;
      int gr = row0 + r;
      float4 v0 = {}, v1 = {}, v2 = {}, v3 = {};
      if (gr < M) {
        const float4* src = (const float4*)(A + (size_t)gr * F_IN + k0 + ch * 16);
        v0 = src[0]; v1 = src[1]; v2 = src[2]; v3 = src[3];
      }
      *(uint4*)&smA[r * 32 + ch * 16]     = pack8(v0, v1);
      *(uint4*)&smA[r * 32 + ch * 16 + 8] = pack8(v2, v3);
    }
#pragma unroll
    for (int q = 0; q < 2; ++q) {
      int idx = q * 256 + tid;           // 0..511
      int r = idx >> 2;                  // 0..127
      int koff = (idx & 3) * 8;
      gl_lds16(W + (size_t)r * F_IN + k0 + koff, &smW[r * 32 + koff]);
    }
    __syncthreads();
    bf16x8 aF[4], bF[4];
#pragma unroll
    for (int i = 0; i < 4; ++i)
      aF[i] = *(const bf16x8*)&smA[(wr * 64 + i * 16 + lr) * 32 + kg * 8];
#pragma unroll
    for (int j = 0; j < 4; ++j)
      bF[j] = *(const bf16x8*)&smW[(wc * 64 + j * 16 + lr) * 32 + kg * 8];
#pragma unroll
    for (int i = 0; i < 4; ++i)
#pragma unroll
      for (int j = 0; j < 4; ++j)
        acc[i][j] = __builtin_amdgcn_mfma_f32_16x16x32_bf16(aF[i], bF[j], acc[i][j], 0, 0, 0);
  }

  __syncthreads();
  float bn[4];
#pragma unroll
  for (int j = 0; j < 4; ++j) bn[j] = bias[wc * 64 + j * 16 + lr];
  unsigned short* ow = sm + w * 4096;
#pragma unroll
  for (int i = 0; i < 4; ++i)
#pragma unroll
    for (int j = 0; j < 4; ++j) {
      f32x4 v = acc[i][j];
#pragma unroll
      for (int r = 0; r < 4; ++r)
        ow[(i * 16 + kg * 4 + r) * 64 + j * 16 + lr] = f2bs(v[r] + bn[j]);
    }
  __syncthreads();
#pragma unroll
  for (int q = 0; q < 8; ++q) {
    int u = q * 64 + l;
    int lrow = u >> 3;
    int cu = (u & 7) * 8;
    int gr = row0 + wr * 64 + lrow;
    if (gr < M)
      *(uint4*)(out + (size_t)gr * D + wc * 64 + cu) = *(const uint4*)&ow[lrow * 64 + cu];
  }
}

// ================= classifier =================

__global__ __launch_bounds__(256) void classify_k(
    const unsigned short* __restrict__ ht, const unsigned short* __restrict__ hm,
    const int* __restrict__ qs, const int* __restrict__ qd,
    const float* __restrict__ w, const float* __restrict__ bptr,
    float* __restrict__ out, int Q)
{
  int g = blockIdx.x * 8 + (threadIdx.x >> 5);
  if (g >= Q) return;
  int l = threadIdx.x & 31;
  const unsigned short* src = (l < 16)
      ? ht + (size_t)qs[g] * D + l * 8
      : hm + (size_t)qd[g] * D + (l - 16) * 8;
  uint4 v = *(const uint4*)src;
  const float* wp = w + l * 8;
  float acc = 0.f;
  acc += b2f(v.x & 0xffffu) * wp[0];
  acc += b2f(v.x >> 16)     * wp[1];
  acc += b2f(v.y & 0xffffu) * wp[2];
  acc += b2f(v.y >> 16)     * wp[3];
  acc += b2f(v.z & 0xffffu) * wp[4];
  acc += b2f(v.z >> 16)     * wp[5];
  acc += b2f(v.w & 0xffffu) * wp[6];
  acc += b2f(v.w >> 16)     * wp[7];
#pragma unroll
  for (int m = 16; m >= 1; m >>= 1) acc += __shfl_xor(acc, m, 64);
  if (l == 0) out[g] = acc + bptr[0];
}

// ================= launcher =================

extern "C" void kernel_launch(void* const* d_in, const int* in_sizes, int n_in,
                              void* d_out, int out_size, void* d_ws, size_t ws_size,
                              hipStream_t stream)
{
  const float* x_thesis = (const float*)d_in[0];
  const int*   mentor_id = (const int*)d_in[1];
  const int*   esrc = (const int*)d_in[2];
  const int*   edst = (const int*)d_in[3];
  const int*   qsrc = (const int*)d_in[4];
  const int*   qdst = (const int*)d_in[5];
  const float* lin_w = (const float*)d_in[6];
  const float* lin_b = (const float*)d_in[7];
  const float* prof  = (const float*)d_in[8];
  const float* Wn_sup = (const float*)d_in[9];
  const float* Wr_sup = (const float*)d_in[10];
  const float* b_sup  = (const float*)d_in[11];
  const float* Wn_rev = (const float*)d_in[12];
  const float* Wr_rev = (const float*)d_in[13];
  const float* b_rev  = (const float*)d_in[14];
  const float* cls_w  = (const float*)d_in[15];
  const float* cls_b  = (const float*)d_in[16];

  const int NT = in_sizes[0] / F_IN;
  const int NM = in_sizes[1];
  const int E  = in_sizes[2];
  const int Q  = in_sizes[4];
  const int L  = in_sizes[11] / D;

  // bucket shifts: ceil(N/2^s) <= 128 and width <= 1024
  int SHT = 0; while ((((NT - 1) >> SHT) + 1) > 128) ++SHT;
  int SHM = 0; while ((((NM - 1) >> SHM) + 1) > 128) ++SHM;
  const int BT = ((NT - 1) >> SHT) + 1;
  const int BM = ((NM - 1) >> SHM) + 1;

  char* wsb = (char*)d_ws;
  size_t off = 0;
  auto alloc = [&](size_t bytes) {
    void* p = wsb + off;
    off = (off + bytes + 255) & ~(size_t)255;
    return p;
  };
  unsigned short* h_t   = (unsigned short*)alloc((size_t)NT * D * 2);
  unsigned short* a_t   = (unsigned short*)alloc((size_t)NT * D * 2);
  unsigned short* h_m   = (unsigned short*)alloc((size_t)NM * D * 2);
  unsigned short* a_m   = (unsigned short*)alloc((size_t)NM * D * 2);
  unsigned short* linw_bf = (unsigned short*)alloc((size_t)D * F_IN * 2);
  unsigned short* wns_bf  = (unsigned short*)alloc((size_t)L * D * D * 2);
  unsigned short* wrs_bf  = (unsigned short*)alloc((size_t)L * D * D * 2);
  unsigned short* wnr_bf  = (unsigned short*)alloc((size_t)L * D * D * 2);
  unsigned short* wrr_bf  = (unsigned short*)alloc((size_t)L * D * D * 2);
  float* invd_t = (float*)alloc((size_t)NT * 4);
  float* invd_m = (float*)alloc((size_t)NM * 4);
  int* row_t = (int*)alloc(((size_t)NT + 1) * 4);
  int* row_m = (int*)alloc(((size_t)NM + 1) * 4);
  int* csr_t = (int*)alloc((size_t)E * 4);
  int* csr_m = (int*)alloc((size_t)E * 4);
  unsigned* partT = (unsigned*)alloc((size_t)E * 4);
  unsigned* partM = (unsigned*)alloc((size_t)E * 4);
  size_t bkt_off = off;
  int* bktT  = (int*)alloc(128 * 4);
  int* bktM  = (int*)alloc(128 * 4);
  size_t bkt_end = off;
  int* baseT = (int*)alloc(129 * 4);
  int* baseM = (int*)alloc(129 * 4);
  int* curT  = (int*)alloc(128 * 4);
  int* curM  = (int*)alloc(128 * 4);
  (void)n_in; (void)out_size; (void)ws_size;

  hipMemsetAsync(wsb + bkt_off, 0, bkt_end - bkt_off, stream);

  // prep: weight converts + prof gather + bucket histogram
  {
    int n0 = D * F_IN / 8, nw = L * D * D / 8;
    int totc = n0 + 4 * nw;
    int nbC = (totc + 255) / 256;
    int nbG = (NM * 16 + 255) / 256;
    int nbA = 256;
    prep_k<<<nbC + nbG + nbA, 256, 0, stream>>>(
        lin_w, linw_bf, n0, Wn_sup, wns_bf, nw, Wr_sup, wrs_bf, nw,
        Wn_rev, wnr_bf, nw, Wr_rev, wrr_bf, nw, nbC,
        prof, mentor_id, h_m, NM, nbG,
        esrc, edst, bktT, bktM, E, SHT, SHM, nbA);
  }
  a2_scan_k<<<1, 256, 0, stream>>>(bktT, baseT, curT, BT, bktM, baseM, curM, BM);
  a3_part_k<<<(E + CH - 1) / CH, 256, 0, stream>>>(
      esrc, edst, partT, partM, curT, curM, E, BT, BM, SHT, SHM);
  b_csr_k<<<BT + BM, 256, 0, stream>>>(
      partT, baseT, row_t, invd_t, csr_t, NT, BT, SHT,
      partM, baseM, row_m, invd_m, csr_m, NM, BM, SHM, E);

  // encoder: h_t = x @ lin_w^T + lin_b (fp32 A converted in-kernel)
  gemm_enc_k<<<(NT + 127) / 128, 256, 0, stream>>>(x_thesis, linw_bf, lin_b, h_t, NT);

  int agg_nbm = (NM + 3) / 4, agg_nbt = (NT + 3) / 4;
  int gem_nbm = (NM + 127) / 128, gem_nbt = (NT + 127) / 128;
  for (int l = 0; l < L; ++l) {
    aggregate2_k<<<agg_nbm + agg_nbt, 256, 0, stream>>>(
        h_t, row_m, csr_m, invd_m, a_m, NM, agg_nbm,
        h_m, row_t, csr_t, invd_t, a_t, NT);

    const unsigned short* wns = wns_bf + (size_t)l * D * D;
    const unsigned short* wrs = wrs_bf + (size_t)l * D * D;
    const unsigned short* wnr = wnr_bf + (size_t)l * D * D;
    const unsigned short* wrr = wrr_bf + (size_t)l * D * D;
    const float* bs = b_sup + (size_t)l * D;
    const float* br = b_rev + (size_t)l * D;
    if (l < L - 1) {
      gemm_pair_k<true><<<gem_nbm + gem_nbt, 256, 0, stream>>>(
          a_m, wns, h_m, wrs, bs, a_m, NM, gem_nbm,
          a_t, wnr, h_t, wrr, br, a_t, NT);
    } else {
      gemm_pair_k<false><<<gem_nbm + gem_nbt, 256, 0, stream>>>(
          a_m, wns, h_m, wrs, bs, a_m, NM, gem_nbm,
          a_t, wnr, h_t, wrr, br, a_t, NT);
    }
    unsigned short* tmp;
    tmp = h_t; h_t = a_t; a_t = tmp;
    tmp = h_m; h_m = a_m; a_m = tmp;
  }

  classify_k<<<(Q + 7) / 8, 256, 0, stream>>>(h_t, h_m, qsrc, qdst, cls_w, cls_b,
                                              (float*)d_out, Q);
}

// Round 6
// 270.611 us; speedup vs baseline: 4.8589x; 1.1048x over previous
//
#include <hip/hip_runtime.h>
#include <cstdint>
#include <cstddef>

#define D 128
#define F_IN 256

typedef __attribute__((ext_vector_type(8))) short bf16x8;
typedef __attribute__((ext_vector_type(4))) float f32x4;

__device__ __forceinline__ unsigned short f2bs(float f) {
  unsigned int x = __builtin_bit_cast(unsigned int, f);
  x = x + 0x7fffu + ((x >> 16) & 1u);           // round-to-nearest-even
  return (unsigned short)(x >> 16);
}
__device__ __forceinline__ float b2f(unsigned int lo16) {
  unsigned int x = lo16 << 16;
  return __builtin_bit_cast(float, x);
}
__device__ __forceinline__ void gl_lds16v(const void* g, void* l) {
  __builtin_amdgcn_global_load_lds(
      (__attribute__((address_space(1))) void*)g,
      (__attribute__((address_space(3))) void*)l, 16, 0, 0);
}
__device__ __forceinline__ uint4 pack8(float4 a, float4 b) {
  uint4 o;
  o.x = (unsigned)f2bs(a.x) | ((unsigned)f2bs(a.y) << 16);
  o.y = (unsigned)f2bs(a.z) | ((unsigned)f2bs(a.w) << 16);
  o.z = (unsigned)f2bs(b.x) | ((unsigned)f2bs(b.y) << 16);
  o.w = (unsigned)f2bs(b.z) | ((unsigned)f2bs(b.w) << 16);
  return o;
}

// ================= prep: weight converts + prof gather + bucket histogram =================

__global__ __launch_bounds__(256) void prep_k(
    const float* __restrict__ s0, unsigned short* __restrict__ d0, int n0,
    const float* __restrict__ s1, unsigned short* __restrict__ d1, int n1,
    const float* __restrict__ s2, unsigned short* __restrict__ d2, int n2,
    const float* __restrict__ s3, unsigned short* __restrict__ d3, int n3,
    const float* __restrict__ s4, unsigned short* __restrict__ d4, int n4,
    int nbC,
    const float* __restrict__ emb, const int* __restrict__ ids,
    unsigned short* __restrict__ hm, int NM, int nbG,
    const int* __restrict__ esrc, const int* __restrict__ edst,
    int* __restrict__ bktT, int* __restrict__ bktM,
    int E, int SHT, int SHM, int nbA)
{
  int bid = blockIdx.x;
  int tid = threadIdx.x;
  if (bid < nbC) {
    int j = bid * 256 + tid;
    const float* s; unsigned short* d;
    if (j < n0) { s = s0; d = d0; }
    else {
      j -= n0;
      if (j < n1) { s = s1; d = d1; }
      else {
        j -= n1;
        if (j < n2) { s = s2; d = d2; }
        else {
          j -= n2;
          if (j < n3) { s = s3; d = d3; }
          else { j -= n3; if (j >= n4) return; s = s4; d = d4; }
        }
      }
    }
    const float4* sp = (const float4*)(s + (size_t)j * 8);
    *(uint4*)(d + (size_t)j * 8) = pack8(sp[0], sp[1]);
    return;
  }
  bid -= nbC;
  if (bid < nbG) {
    int i = bid * 256 + tid;
    if (i >= NM * 16) return;
    int r = i >> 4, c = (i & 15) * 8;
    const float* s = emb + (size_t)ids[r] * D + c;
    *(uint4*)(hm + (size_t)r * D + c) = pack8(*(const float4*)s, *(const float4*)(s + 4));
    return;
  }
  bid -= nbG;
  __shared__ int sh[256];
  sh[tid] = 0;
  __syncthreads();
  int stride = nbA * 256;
  for (int e = bid * 256 + tid; e < E; e += stride) {
    atomicAdd(&sh[esrc[e] >> SHT], 1);
    atomicAdd(&sh[128 + (edst[e] >> SHM)], 1);
  }
  __syncthreads();
  if (tid < 128) { if (sh[tid]) atomicAdd(&bktT[tid], sh[tid]); }
  else { if (sh[tid]) atomicAdd(&bktM[tid - 128], sh[tid]); }
}

// ================= A2: scan bucket counts -> bases + cursors =================

__global__ void a2_scan_k(const int* __restrict__ bktT, int* __restrict__ baseT, int* __restrict__ curT, int BT,
                          const int* __restrict__ bktM, int* __restrict__ baseM, int* __restrict__ curM, int BM) {
  __shared__ int sT[129], sM[129];
  int tid = threadIdx.x;
  if (tid < BT) sT[tid] = bktT[tid];
  if (tid < BM) sM[tid] = bktM[tid];
  __syncthreads();
  if (tid == 0) { int r = 0; for (int i = 0; i < BT; ++i) { int c = sT[i]; sT[i] = r; r += c; } sT[BT] = r; }
  if (tid == 1) { int r = 0; for (int i = 0; i < BM; ++i) { int c = sM[i]; sM[i] = r; r += c; } sM[BM] = r; }
  __syncthreads();
  if (tid <= BT) { baseT[tid] = sT[tid]; if (tid < BT) curT[tid] = sT[tid]; }
  if (tid <= BM) { baseM[tid] = sM[tid]; if (tid < BM) curM[tid] = sM[tid]; }
}

// ================= A3: multi-split partition with LDS staging =================

#define CH 4096

__global__ __launch_bounds__(256) void a3_part_k(
    const int* __restrict__ esrc, const int* __restrict__ edst,
    unsigned* __restrict__ partT, unsigned* __restrict__ partM,
    int* __restrict__ curT, int* __restrict__ curM,
    int E, int BT, int BM, int SHT, int SHM)
{
  __shared__ unsigned stT[CH], stM[CH];
  __shared__ int hT[128], lbT[128], lcT[128], gbT[128];
  __shared__ int hM[128], lbM[128], lcM[128], gbM[128];
  __shared__ int st2[256];
  int tid = threadIdx.x;
  int c0 = blockIdx.x * CH;
  int len = E - c0; if (len > CH) len = CH;

  if (tid < 128) { hT[tid] = 0; hM[tid] = 0; }
  __syncthreads();
  for (int i = tid; i < len; i += 256) {
    atomicAdd(&hT[esrc[c0 + i] >> SHT], 1);
    atomicAdd(&hM[edst[c0 + i] >> SHM], 1);
  }
  __syncthreads();
  int own = (tid < 128) ? hT[tid] : hM[tid - 128];
  st2[tid] = own;
  __syncthreads();
  for (int dd = 1; dd < 128; dd <<= 1) {
    int y = ((tid & 127) >= dd) ? st2[tid - dd] : 0;
    __syncthreads();
    st2[tid] += y;
    __syncthreads();
  }
  int excl = st2[tid] - own;
  if (tid < 128) { lbT[tid] = excl; lcT[tid] = excl; }
  else { lbM[tid - 128] = excl; lcM[tid - 128] = excl; }
  __syncthreads();
  if (tid < BT) { if (hT[tid]) gbT[tid] = atomicAdd(&curT[tid], hT[tid]); }
  if (tid >= 128 && tid - 128 < BM) { int m = tid - 128; if (hM[m]) gbM[m] = atomicAdd(&curM[m], hM[m]); }
  __syncthreads();
  for (int i = tid; i < len; i += 256) {
    unsigned s = (unsigned)esrc[c0 + i], dn = (unsigned)edst[c0 + i];
    int p = atomicAdd(&lcT[s >> SHT], 1);
    stT[p] = (s << 15) | dn;
    int q = atomicAdd(&lcM[dn >> SHM], 1);
    stM[q] = (dn << 17) | s;
  }
  __syncthreads();
  for (int b = 0; b < BT; ++b) {
    int cb = hT[b]; if (!cb) continue;
    int lb = lbT[b]; int gb = gbT[b];
    for (int i = tid; i < cb; i += 256) partT[gb + i] = stT[lb + i];
  }
  for (int b = 0; b < BM; ++b) {
    int cb = hM[b]; if (!cb) continue;
    int lb = lbM[b]; int gb = gbM[b];
    for (int i = tid; i < cb; i += 256) partM[gb + i] = stM[lb + i];
  }
}

// ================= B: per-bucket CSR finalize (rowptr, csr) =================

#define BCAP 12288

__global__ __launch_bounds__(256) void b_csr_k(
    const unsigned* __restrict__ partT, const int* __restrict__ baseT,
    int* __restrict__ rowT, int* __restrict__ csrT, int NT, int BT, int SHT,
    const unsigned* __restrict__ partM, const int* __restrict__ baseM,
    int* __restrict__ rowM, int* __restrict__ csrM, int NM, int BM, int SHM, int E)
{
  __shared__ int cnt[1024];
  __shared__ int st[256];
  __shared__ unsigned stage[BCAP];

  const unsigned* part; const int* base; int* row; int* csr;
  int N, SH, KS; unsigned PM; int b; bool last;
  if ((int)blockIdx.x < BT) {
    part = partT; base = baseT; row = rowT; csr = csrT;
    N = NT; SH = SHT; KS = 15; PM = 0x7fffu; b = blockIdx.x; last = (b == BT - 1);
  } else {
    part = partM; base = baseM; row = rowM; csr = csrM;
    N = NM; SH = SHM; KS = 17; PM = 0x1ffffu; b = blockIdx.x - BT; last = (b == BM - 1);
  }
  int tid = threadIdx.x;
  int ebeg = base[b], eend = base[b + 1];
  int tot = eend - ebeg;
  int n0 = b << SH;
  int width = 1 << SH;
  int nw = N - n0; if (nw > width) nw = width;
  int seg = (width + 255) >> 8;

  for (int j = 0; j < seg; ++j) { int idx = tid * seg + j; if (idx < nw) cnt[idx] = 0; }
  __syncthreads();
  for (int i = tid; i < tot; i += 256) {
    int k = (int)(part[ebeg + i] >> KS) - n0;
    atomicAdd(&cnt[k], 1);
  }
  __syncthreads();
  int s = 0;
  for (int j = 0; j < seg; ++j) { int idx = tid * seg + j; if (idx < nw) s += cnt[idx]; }
  st[tid] = s;
  __syncthreads();
  for (int dd = 1; dd < 256; dd <<= 1) {
    int y = (tid >= dd) ? st[tid - dd] : 0;
    __syncthreads();
    st[tid] += y;
    __syncthreads();
  }
  int run = st[tid] - s;
  for (int j = 0; j < seg; ++j) {
    int idx = tid * seg + j;
    if (idx < nw) {
      int c = cnt[idx];
      row[n0 + idx] = ebeg + run;
      cnt[idx] = run;
      run += c;
    }
  }
  if (last && tid == 0) row[N] = E;
  __syncthreads();
  if (tot <= BCAP) {
    for (int i = tid; i < tot; i += 256) {
      unsigned p = part[ebeg + i];
      int k = (int)(p >> KS) - n0;
      int pos = atomicAdd(&cnt[k], 1);
      stage[pos] = p & PM;
    }
    __syncthreads();
    for (int i = tid; i < tot; i += 256) csr[ebeg + i] = (int)stage[i];
  } else {
    for (int i = tid; i < tot; i += 256) {
      unsigned p = part[ebeg + i];
      int k = (int)(p >> KS) - n0;
      int pos = atomicAdd(&cnt[k], 1);
      csr[ebeg + pos] = (int)(p & PM);
    }
  }
}

// ================= aggregation: 2 nodes per wave (32-lane halves), deep ILP =================

__global__ __launch_bounds__(256) void aggregate2_k(
    const unsigned short* __restrict__ tabM, const int* __restrict__ rowpM,
    const int* __restrict__ idxM, unsigned short* __restrict__ outM, int nM, int nblkM,
    const unsigned short* __restrict__ tabT, const int* __restrict__ rowpT,
    const int* __restrict__ idxT, unsigned short* __restrict__ outT, int nT)
{
  const unsigned short* tab; const int* rowp; const int* idx;
  unsigned short* outp; int n, nodeb;
  if ((int)blockIdx.x < nblkM) {
    tab = tabM; rowp = rowpM; idx = idxM; outp = outM; n = nM;
    nodeb = blockIdx.x * 8;
  } else {
    tab = tabT; rowp = rowpT; idx = idxT; outp = outT; n = nT;
    nodeb = (blockIdx.x - nblkM) * 8;
  }
  const int tid = threadIdx.x;
  const int l = tid & 63;
  const int l32 = l & 31;
  const int sub = l >> 5;
  const int node = nodeb + (tid >> 6) * 2 + sub;
  const int nodeC = node < n ? node : n - 1;
  int b = rowp[nodeC];
  int e = rowp[nodeC + 1];
  if (node >= n) e = b;
  const int deg = e - b;
  const int odeg = __shfl_xor(deg, 32, 64);
  const int trip = deg > odeg ? deg : odeg;
  const int qsafe = (e > b) ? (e - 1) : 0;
  const unsigned short* tl = tab + l32 * 4;
  float a0 = 0.f, a1 = 0.f, a2 = 0.f, a3 = 0.f;
  int k = 0;
  while (k + 8 <= trip) {
    int nn[8]; bool ok[8];
#pragma unroll
    for (int u = 0; u < 8; ++u) { int p = b + k + u; ok[u] = p < e; nn[u] = idx[ok[u] ? p : qsafe]; }
    uint2 vv[8];
#pragma unroll
    for (int u = 0; u < 8; ++u) { vv[u] = make_uint2(0u, 0u); if (ok[u]) vv[u] = *(const uint2*)(tl + (size_t)nn[u] * D); }
#pragma unroll
    for (int u = 0; u < 8; ++u) {
      a0 += b2f(vv[u].x & 0xffffu); a1 += b2f(vv[u].x >> 16);
      a2 += b2f(vv[u].y & 0xffffu); a3 += b2f(vv[u].y >> 16);
    }
    k += 8;
  }
  if (k + 4 <= trip) {
    int nn[4]; bool ok[4];
#pragma unroll
    for (int u = 0; u < 4; ++u) { int p = b + k + u; ok[u] = p < e; nn[u] = idx[ok[u] ? p : qsafe]; }
    uint2 vv[4];
#pragma unroll
    for (int u = 0; u < 4; ++u) { vv[u] = make_uint2(0u, 0u); if (ok[u]) vv[u] = *(const uint2*)(tl + (size_t)nn[u] * D); }
#pragma unroll
    for (int u = 0; u < 4; ++u) {
      a0 += b2f(vv[u].x & 0xffffu); a1 += b2f(vv[u].x >> 16);
      a2 += b2f(vv[u].y & 0xffffu); a3 += b2f(vv[u].y >> 16);
    }
    k += 4;
  }
  if (k < trip) {
    int nn[3]; bool ok[3];
#pragma unroll
    for (int u = 0; u < 3; ++u) { int p = b + k + u; ok[u] = p < e; nn[u] = idx[ok[u] ? p : qsafe]; }
    uint2 vv[3];
#pragma unroll
    for (int u = 0; u < 3; ++u) { vv[u] = make_uint2(0u, 0u); if (ok[u]) vv[u] = *(const uint2*)(tl + (size_t)nn[u] * D); }
#pragma unroll
    for (int u = 0; u < 3; ++u) {
      a0 += b2f(vv[u].x & 0xffffu); a1 += b2f(vv[u].x >> 16);
      a2 += b2f(vv[u].y & 0xffffu); a3 += b2f(vv[u].y >> 16);
    }
  }
  float inv = 1.0f / (float)(deg > 1 ? deg : 1);
  if (node < n) {
    uint2 o;
    o.x = (unsigned)f2bs(a0 * inv) | ((unsigned)f2bs(a1 * inv) << 16);
    o.y = (unsigned)f2bs(a2 * inv) | ((unsigned)f2bs(a3 * inv) << 16);
    *(uint2*)(outp + (size_t)node * D + l32 * 4) = o;
  }
}

// ================= bf16 MFMA fused dual GEMM (2-phase pipeline, swizzled LDS) =================

template<bool RELU>
__device__ __forceinline__ void gemm_body(
    const unsigned short* __restrict__ Aop, const unsigned short* __restrict__ WA,
    const unsigned short* __restrict__ Bop, const unsigned short* __restrict__ WB,
    const float* __restrict__ bias, unsigned short* __restrict__ out, int M,
    int blk, char* smraw)
{
  unsigned short* bufA0 = (unsigned short*)smraw;            // [2][4096]
  unsigned short* bufW0 = (unsigned short*)(smraw + 16384);  // [2][4096]
  const int tid = threadIdx.x;
  const int w = tid >> 6, l = tid & 63;
  const int wr = w >> 1, wc = w & 1;
  const int lr = l & 15, kg = l >> 4;
  const int row0 = blk * 128;
  const int srow = l >> 2;   // 0..15
  const int su = l & 3;      // 16B unit

  f32x4 acc[4][4] = {};

  auto stage = [&](int st, int bsel) {
    const unsigned short* Ap = (st < 4) ? Aop : Bop;
    const unsigned short* Wp = (st < 4) ? WA : WB;
    int k0 = (st & 3) * 32;
    unsigned short* bA = bufA0 + bsel * 4096;
    unsigned short* bW = bufW0 + bsel * 4096;
#pragma unroll
    for (int q = 0; q < 2; ++q) {
      int r = w * 32 + q * 16 + srow;
      int gr = row0 + r; if (gr >= M) gr = M - 1;   // clamp: keeps vmcnt counts uniform
      int gu = su ^ ((r >> 1) & 3);
      gl_lds16v(Ap + (size_t)gr * D + k0 + gu * 8, bA + (w * 32 + q * 16) * 32 + l * 8);
      gl_lds16v(Wp + (size_t)r * D + k0 + gu * 8, bW + (w * 32 + q * 16) * 32 + l * 8);
    }
  };

  stage(0, 0);
#pragma unroll 1
  for (int st = 0; st < 8; ++st) {
    if (st < 7) {
      stage(st + 1, (st + 1) & 1);
      __builtin_amdgcn_sched_barrier(0);
      asm volatile("s_waitcnt vmcnt(4)" ::: "memory");
    } else {
      __builtin_amdgcn_sched_barrier(0);
      asm volatile("s_waitcnt vmcnt(0)" ::: "memory");
    }
    __builtin_amdgcn_s_barrier();
    __builtin_amdgcn_sched_barrier(0);
    const unsigned short* bA = bufA0 + (st & 1) * 4096;
    const unsigned short* bW = bufW0 + (st & 1) * 4096;
    bf16x8 aF[4], bF[4];
#pragma unroll
    for (int i = 0; i < 4; ++i) {
      int r = wr * 64 + i * 16 + lr;
      aF[i] = *(const bf16x8*)&bA[r * 32 + ((kg ^ ((r >> 1) & 3)) * 8)];
    }
#pragma unroll
    for (int j = 0; j < 4; ++j) {
      int r = wc * 64 + j * 16 + lr;
      bF[j] = *(const bf16x8*)&bW[r * 32 + ((kg ^ ((r >> 1) & 3)) * 8)];
    }
#pragma unroll
    for (int i = 0; i < 4; ++i)
#pragma unroll
      for (int j = 0; j < 4; ++j)
        acc[i][j] = __builtin_amdgcn_mfma_f32_16x16x32_bf16(aF[i], bF[j], acc[i][j], 0, 0, 0);
    __builtin_amdgcn_sched_barrier(0);
    __builtin_amdgcn_s_barrier();
  }

  __syncthreads();
  float bn[4];
#pragma unroll
  for (int j = 0; j < 4; ++j) bn[j] = bias[wc * 64 + j * 16 + lr];
  unsigned short* ow = (unsigned short*)smraw + w * 4096;
#pragma unroll
  for (int i = 0; i < 4; ++i)
#pragma unroll
    for (int j = 0; j < 4; ++j) {
      f32x4 v = acc[i][j];
#pragma unroll
      for (int r = 0; r < 4; ++r) {
        float x = v[r] + bn[j];
        if (RELU) x = fmaxf(x, 0.f);
        ow[(i * 16 + kg * 4 + r) * 64 + j * 16 + lr] = f2bs(x);
      }
    }
  __syncthreads();
#pragma unroll
  for (int q = 0; q < 8; ++q) {
    int u = q * 64 + l;
    int lrow = u >> 3;
    int cu = (u & 7) * 8;
    int gr = row0 + wr * 64 + lrow;
    if (gr < M)
      *(uint4*)(out + (size_t)gr * D + wc * 64 + cu) = *(const uint4*)&ow[lrow * 64 + cu];
  }
}

template<bool RELU>
__global__ __launch_bounds__(256) void gemm_pair_k(
    const unsigned short* __restrict__ Am, const unsigned short* __restrict__ WAm,
    const unsigned short* __restrict__ Bm, const unsigned short* __restrict__ WBm,
    const float* __restrict__ biasm, unsigned short* __restrict__ outm, int Mm, int nbm,
    const unsigned short* __restrict__ At, const unsigned short* __restrict__ WAt,
    const unsigned short* __restrict__ Bt, const unsigned short* __restrict__ WBt,
    const float* __restrict__ biast, unsigned short* __restrict__ outt, int Mt)
{
  __shared__ char smraw[32768];
  if ((int)blockIdx.x < nbm)
    gemm_body<RELU>(Am, WAm, Bm, WBm, biasm, outm, Mm, blockIdx.x, smraw);
  else
    gemm_body<RELU>(At, WAt, Bt, WBt, biast, outt, Mt, blockIdx.x - nbm, smraw);
}

// encoder GEMM: A fp32 staged raw via global_load_lds (swizzled), cvt in-register
__global__ __launch_bounds__(256) void gemm_enc_k(
    const float* __restrict__ A, const unsigned short* __restrict__ W,
    const float* __restrict__ bias, unsigned short* __restrict__ out, int M)
{
  __shared__ char smraw[49152];
  float* bufA0 = (float*)smraw;                              // [2][4096] f32
  unsigned short* bufW0 = (unsigned short*)(smraw + 32768);  // [2][4096] bf16
  const int tid = threadIdx.x;
  const int w = tid >> 6, l = tid & 63;
  const int wr = w >> 1, wc = w & 1;
  const int lr = l & 15, kg = l >> 4;
  const int row0 = blockIdx.x * 128;
  const int arow = l >> 3;   // A: 8 rows per instr
  const int au = l & 7;      // A: 16B unit (4 f32)
  const int wrow = l >> 2;   // W: 16 rows per instr
  const int wu = l & 3;

  f32x4 acc[4][4] = {};

  auto stage = [&](int st, int bsel) {
    int k0 = st * 32;
    float* bA = bufA0 + bsel * 4096;
    unsigned short* bW = bufW0 + bsel * 4096;
#pragma unroll
    for (int q = 0; q < 4; ++q) {
      int r = w * 32 + q * 8 + arow;
      int gr = row0 + r; if (gr >= M) gr = M - 1;
      int gu = au ^ (r & 7);
      gl_lds16v(A + (size_t)gr * F_IN + k0 + gu * 4, bA + (w * 32 + q * 8) * 32 + l * 4);
    }
#pragma unroll
    for (int q = 0; q < 2; ++q) {
      int r = w * 32 + q * 16 + wrow;
      int gu = wu ^ ((r >> 1) & 3);
      gl_lds16v(W + (size_t)r * F_IN + k0 + gu * 8, bW + (w * 32 + q * 16) * 32 + l * 8);
    }
  };

  stage(0, 0);
#pragma unroll 1
  for (int st = 0; st < F_IN / 32; ++st) {
    if (st < F_IN / 32 - 1) {
      stage(st + 1, (st + 1) & 1);
      __builtin_amdgcn_sched_barrier(0);
      asm volatile("s_waitcnt vmcnt(6)" ::: "memory");
    } else {
      __builtin_amdgcn_sched_barrier(0);
      asm volatile("s_waitcnt vmcnt(0)" ::: "memory");
    }
    __builtin_amdgcn_s_barrier();
    __builtin_amdgcn_sched_barrier(0);
    const float* bA = bufA0 + (st & 1) * 4096;
    const unsigned short* bW = bufW0 + (st & 1) * 4096;
    bf16x8 aF[4], bF[4];
#pragma unroll
    for (int i = 0; i < 4; ++i) {
      int r = wr * 64 + i * 16 + lr;
      const float4* pa = (const float4*)(bA + r * 32);
      float4 v0 = pa[(2 * kg) ^ (r & 7)];
      float4 v1 = pa[(2 * kg + 1) ^ (r & 7)];
      uint4 c = pack8(v0, v1);
      aF[i] = *(bf16x8*)&c;
    }
#pragma unroll
    for (int j = 0; j < 4; ++j) {
      int r = wc * 64 + j * 16 + lr;
      bF[j] = *(const bf16x8*)&bW[r * 32 + ((kg ^ ((r >> 1) & 3)) * 8)];
    }
#pragma unroll
    for (int i = 0; i < 4; ++i)
#pragma unroll
      for (int j = 0; j < 4; ++j)
        acc[i][j] = __builtin_amdgcn_mfma_f32_16x16x32_bf16(aF[i], bF[j], acc[i][j], 0, 0, 0);
    __builtin_amdgcn_sched_barrier(0);
    __builtin_amdgcn_s_barrier();
  }

  __syncthreads();
  float bn[4];
#pragma unroll
  for (int j = 0; j < 4; ++j) bn[j] = bias[wc * 64 + j * 16 + lr];
  unsigned short* ow = (unsigned short*)smraw + w * 4096;
#pragma unroll
  for (int i = 0; i < 4; ++i)
#pragma unroll
    for (int j = 0; j < 4; ++j) {
      f32x4 v = acc[i][j];
#pragma unroll
      for (int r = 0; r < 4; ++r)
        ow[(i * 16 + kg * 4 + r) * 64 + j * 16 + lr] = f2bs(v[r] + bn[j]);
    }
  __syncthreads();
#pragma unroll
  for (int q = 0; q < 8; ++q) {
    int u = q * 64 + l;
    int lrow = u >> 3;
    int cu = (u & 7) * 8;
    int gr = row0 + wr * 64 + lrow;
    if (gr < M)
      *(uint4*)(out + (size_t)gr * D + wc * 64 + cu) = *(const uint4*)&ow[lrow * 64 + cu];
  }
}

// ================= classifier =================

__global__ __launch_bounds__(256) void classify_k(
    const unsigned short* __restrict__ ht, const unsigned short* __restrict__ hm,
    const int* __restrict__ qs, const int* __restrict__ qd,
    const float* __restrict__ w, const float* __restrict__ bptr,
    float* __restrict__ out, int Q)
{
  int g = blockIdx.x * 8 + (threadIdx.x >> 5);
  if (g >= Q) return;
  int l = threadIdx.x & 31;
  const unsigned short* src = (l < 16)
      ? ht + (size_t)qs[g] * D + l * 8
      : hm + (size_t)qd[g] * D + (l - 16) * 8;
  uint4 v = *(const uint4*)src;
  const float* wp = w + l * 8;
  float acc = 0.f;
  acc += b2f(v.x & 0xffffu) * wp[0];
  acc += b2f(v.x >> 16)     * wp[1];
  acc += b2f(v.y & 0xffffu) * wp[2];
  acc += b2f(v.y >> 16)     * wp[3];
  acc += b2f(v.z & 0xffffu) * wp[4];
  acc += b2f(v.z >> 16)     * wp[5];
  acc += b2f(v.w & 0xffffu) * wp[6];
  acc += b2f(v.w >> 16)     * wp[7];
#pragma unroll
  for (int m = 16; m >= 1; m >>= 1) acc += __shfl_xor(acc, m, 64);
  if (l == 0) out[g] = acc + bptr[0];
}

// ================= launcher =================

extern "C" void kernel_launch(void* const* d_in, const int* in_sizes, int n_in,
                              void* d_out, int out_size, void* d_ws, size_t ws_size,
                              hipStream_t stream)
{
  const float* x_thesis = (const float*)d_in[0];
  const int*   mentor_id = (const int*)d_in[1];
  const int*   esrc = (const int*)d_in[2];
  const int*   edst = (const int*)d_in[3];
  const int*   qsrc = (const int*)d_in[4];
  const int*   qdst = (const int*)d_in[5];
  const float* lin_w = (const float*)d_in[6];
  const float* lin_b = (const float*)d_in[7];
  const float* prof  = (const float*)d_in[8];
  const float* Wn_sup = (const float*)d_in[9];
  const float* Wr_sup = (const float*)d_in[10];
  const float* b_sup  = (const float*)d_in[11];
  const float* Wn_rev = (const float*)d_in[12];
  const float* Wr_rev = (const float*)d_in[13];
  const float* b_rev  = (const float*)d_in[14];
  const float* cls_w  = (const float*)d_in[15];
  const float* cls_b  = (const float*)d_in[16];

  const int NT = in_sizes[0] / F_IN;
  const int NM = in_sizes[1];
  const int E  = in_sizes[2];
  const int Q  = in_sizes[4];
  const int L  = in_sizes[11] / D;

  int SHT = 0; while ((((NT - 1) >> SHT) + 1) > 128) ++SHT;
  int SHM = 0; while ((((NM - 1) >> SHM) + 1) > 128) ++SHM;
  const int BT = ((NT - 1) >> SHT) + 1;
  const int BM = ((NM - 1) >> SHM) + 1;

  char* wsb = (char*)d_ws;
  size_t off = 0;
  auto alloc = [&](size_t bytes) {
    void* p = wsb + off;
    off = (off + bytes + 255) & ~(size_t)255;
    return p;
  };
  unsigned short* h_t   = (unsigned short*)alloc((size_t)NT * D * 2);
  unsigned short* a_t   = (unsigned short*)alloc((size_t)NT * D * 2);
  unsigned short* h_m   = (unsigned short*)alloc((size_t)NM * D * 2);
  unsigned short* a_m   = (unsigned short*)alloc((size_t)NM * D * 2);
  unsigned short* linw_bf = (unsigned short*)alloc((size_t)D * F_IN * 2);
  unsigned short* wns_bf  = (unsigned short*)alloc((size_t)L * D * D * 2);
  unsigned short* wrs_bf  = (unsigned short*)alloc((size_t)L * D * D * 2);
  unsigned short* wnr_bf  = (unsigned short*)alloc((size_t)L * D * D * 2);
  unsigned short* wrr_bf  = (unsigned short*)alloc((size_t)L * D * D * 2);
  int* row_t = (int*)alloc(((size_t)NT + 1) * 4);
  int* row_m = (int*)alloc(((size_t)NM + 1) * 4);
  int* csr_t = (int*)alloc((size_t)E * 4);
  int* csr_m = (int*)alloc((size_t)E * 4);
  unsigned* partT = (unsigned*)alloc((size_t)E * 4);
  unsigned* partM = (unsigned*)alloc((size_t)E * 4);
  size_t bkt_off = off;
  int* bktT  = (int*)alloc(128 * 4);
  int* bktM  = (int*)alloc(128 * 4);
  size_t bkt_end = off;
  int* baseT = (int*)alloc(129 * 4);
  int* baseM = (int*)alloc(129 * 4);
  int* curT  = (int*)alloc(128 * 4);
  int* curM  = (int*)alloc(128 * 4);
  (void)n_in; (void)out_size; (void)ws_size;

  (void)hipMemsetAsync(wsb + bkt_off, 0, bkt_end - bkt_off, stream);

  {
    int n0 = D * F_IN / 8, nw = L * D * D / 8;
    int totc = n0 + 4 * nw;
    int nbC = (totc + 255) / 256;
    int nbG = (NM * 16 + 255) / 256;
    int nbA = 256;
    prep_k<<<nbC + nbG + nbA, 256, 0, stream>>>(
        lin_w, linw_bf, n0, Wn_sup, wns_bf, nw, Wr_sup, wrs_bf, nw,
        Wn_rev, wnr_bf, nw, Wr_rev, wrr_bf, nw, nbC,
        prof, mentor_id, h_m, NM, nbG,
        esrc, edst, bktT, bktM, E, SHT, SHM, nbA);
  }
  a2_scan_k<<<1, 256, 0, stream>>>(bktT, baseT, curT, BT, bktM, baseM, curM, BM);
  a3_part_k<<<(E + CH - 1) / CH, 256, 0, stream>>>(
      esrc, edst, partT, partM, curT, curM, E, BT, BM, SHT, SHM);
  b_csr_k<<<BT + BM, 256, 0, stream>>>(
      partT, baseT, row_t, csr_t, NT, BT, SHT,
      partM, baseM, row_m, csr_m, NM, BM, SHM, E);

  gemm_enc_k<<<(NT + 127) / 128, 256, 0, stream>>>(x_thesis, linw_bf, lin_b, h_t, NT);

  int agg_nbm = (NM + 7) / 8, agg_nbt = (NT + 7) / 8;
  int gem_nbm = (NM + 127) / 128, gem_nbt = (NT + 127) / 128;
  for (int l = 0; l < L; ++l) {
    aggregate2_k<<<agg_nbm + agg_nbt, 256, 0, stream>>>(
        h_t, row_m, csr_m, a_m, NM, agg_nbm,
        h_m, row_t, csr_t, a_t, NT);

    const unsigned short* wns = wns_bf + (size_t)l * D * D;
    const unsigned short* wrs = wrs_bf + (size_t)l * D * D;
    const unsigned short* wnr = wnr_bf + (size_t)l * D * D;
    const unsigned short* wrr = wrr_bf + (size_t)l * D * D;
    const float* bs = b_sup + (size_t)l * D;
    const float* br = b_rev + (size_t)l * D;
    if (l < L - 1) {
      gemm_pair_k<true><<<gem_nbm + gem_nbt, 256, 0, stream>>>(
          a_m, wns, h_m, wrs, bs, a_m, NM, gem_nbm,
          a_t, wnr, h_t, wrr, br, a_t, NT);
    } else {
      gemm_pair_k<false><<<gem_nbm + gem_nbt, 256, 0, stream>>>(
          a_m, wns, h_m, wrs, bs, a_m, NM, gem_nbm,
          a_t, wnr, h_t, wrr, br, a_t, NT);
    }
    unsigned short* tmp;
    tmp = h_t; h_t = a_t; a_t = tmp;
    tmp = h_m; h_m = a_m; a_m = tmp;
  }

  classify_k<<<(Q + 7) / 8, 256, 0, stream>>>(h_t, h_m, qsrc, qdst, cls_w, cls_b,
                                              (float*)d_out, Q);
}